// Round 7
// baseline (116.372 us; speedup 1.0000x reference)
//
#include <hip/hip_runtime.h>
#include <hip/hip_fp16.h>
#include <math.h>

#define NA_ 10000
#define NM_ 150000
#define B_  4
#define NS_ 4
#define NMAX_ 32
#define NO_ 4
#define H1_ 4
#define H2_ 38
#define PPT_ 8
#define PI_F 3.14159265358979323846f

// ---- ws layout (main path) ----
#define CSN_OFF   ((size_t)0)
#define CSN_BYTES ((size_t)B_ * NA_ * NMAX_ * 4)       // 5,120,000
#define REC_OFF   (CSN_OFF + CSN_BYTES)
#define REC_BYTES ((size_t)B_ * NM_ * 8)               // 4,800,000 (packed rec8)
#define R_OFF     (REC_OFF + REC_BYTES)
#define R_BYTES   ((size_t)B_ * NM_ * NMAX_ * 2)       // 38,400,000 (row-major R)
#define ST_OFF    (R_OFF + R_BYTES + 128)
#define ST_BYTES  ((size_t)B_ * (NA_ + 1) * 4 + 16)
#define WS_NEED   (ST_OFF + ST_BYTES)

// ---------------------------------------------------------------------------
// Kernel 0: segment starts from sorted iidx.
// ---------------------------------------------------------------------------
__global__ void starts_kernel(const int* __restrict__ iidx, int* __restrict__ starts) {
    int p = blockIdx.x * blockDim.x + threadIdx.x;
    if (p >= B_ * NM_) return;
    int b = p / NM_, pl = p - b * NM_;
    const int* ii = iidx + (size_t)b * NM_;
    int* st = starts + (size_t)b * (NA_ + 1);
    int cur = ii[pl];
    int prev = (pl == 0) ? -1 : ii[pl - 1];
    for (int a = prev + 1; a <= cur; ++a) st[a] = pl;
    if (pl == NM_ - 1) {
        for (int a = cur + 1; a <= NA_; ++a) st[a] = NM_;
    }
}

// ---------------------------------------------------------------------------
// prep0: pair-parallel (half-wave = 32 lanes = n; PPT_ consecutive pairs per
// half). Writes row-major R[b][p][n] (64B coalesced rows, fp16) and packed
// rec8[p] = { h(x) | h(y)<<16 , h(z) | ((j | jat<<14)<<16) }.
// ---------------------------------------------------------------------------
__global__ __launch_bounds__(256) void prep0_kernel(
    const float* __restrict__ disp, const float* __restrict__ alpha,
    const float* __restrict__ rsp, const int* __restrict__ jidx,
    const int* __restrict__ sorted_numbers,
    unsigned short* __restrict__ R, uint2* __restrict__ rec8)
{
    int wid = (blockIdx.x * 256 + threadIdx.x) >> 6;
    int lane = threadIdx.x & 63;
    int h = lane >> 5, n = lane & 31;
    int gh = wid * 2 + h;                    // [0, B*NM/PPT)
    constexpr int HPI = NM_ / PPT_;
    int b = gh / HPI;
    int pbase = (gh - b * HPI) * PPT_;

    float al0 = alpha[n],      al1 = alpha[32 + n];
    float al2 = alpha[64 + n], al3 = alpha[96 + n];
    float rv0 = rsp[n],        rv1 = rsp[32 + n];
    float rv2 = rsp[64 + n],   rv3 = rsp[96 + n];

    const int* jjb = jidx + (size_t)b * NM_;
    const float* dpb = disp + (size_t)b * NM_ * 3;
    unsigned short* Rb = R + (size_t)b * NM_ * NMAX_;
    uint2* rcb = rec8 + (size_t)b * NM_;

#pragma unroll
    for (int k = 0; k < PPT_; ++k) {
        int p = pbase + k;
        int j = jjb[p];
        float x = dpb[p * 3 + 0];
        float y = dpb[p * 3 + 1];
        float z = dpb[p * 3 + 2];
        int jat = sorted_numbers[j];
        float dist = sqrtf(x * x + y * y + z * z);
        float c = __cosf(dist * (PI_F / 6.0f));
        float fc = 0.25f * (c + 1.f) * (c + 1.f);
        bool s0 = (jat & 1) != 0, s1 = (jat & 2) != 0;
        float av = s1 ? (s0 ? al3 : al2) : (s0 ? al1 : al0);
        float rv = s1 ? (s0 ? rv3 : rv2) : (s0 ? rv1 : rv0);
        float dd = dist - rv;
        Rb[(size_t)p * NMAX_ + n] =
            __half_as_ushort(__float2half_rn(fc * __expf(av * dd * dd)));
        if (n == k) {
            unsigned int ux = (unsigned int)__half_as_ushort(__float2half_rn(x)) |
                              ((unsigned int)__half_as_ushort(__float2half_rn(y)) << 16);
            unsigned int uy = (unsigned int)__half_as_ushort(__float2half_rn(z)) |
                              (((unsigned int)(j | (jat << 14))) << 16);
            rcb[p] = make_uint2(ux, uy);
        }
    }
}

// ---------------------------------------------------------------------------
// pass: one wave = TWO atoms (half-wave each, lane = n). All loads issued in
// the prologue, all independent and COALESCED:
//   - R: 32 scalar ushort loads R[(p0+k)*32+n] (64B/half per instruction)
//   - rec8: lane-owned (lane L holds pair p0+(L&31)), shfl-distributed
//   - (PASS1) csn2 rows gathered upfront (L2-resident)
// Compute is a static 32-pair unroll gated every 4 by wave-uniform mseg.
// Rare seg>32 -> scalar tail. PASS=0 epilogue: MLP -> csn2. PASS=1: rho->out.
// ---------------------------------------------------------------------------
template <int PASS>
__global__ __launch_bounds__(256) void pass_kernel(
    const unsigned short* __restrict__ R, const uint2* __restrict__ rec8,
    const float* __restrict__ spp, const float* __restrict__ op,
    const float* __restrict__ w1, const float* __restrict__ b1,
    const float* __restrict__ w2, const float* __restrict__ b2,
    const float* __restrict__ w3, const float* __restrict__ b3,
    const int* __restrict__ sorted_numbers, const int* __restrict__ starts,
    float* __restrict__ csn2, float* __restrict__ out)
{
    int wave = blockIdx.x * 4 + (threadIdx.x >> 6);
    int lane = threadIdx.x & 63;
    int h = lane >> 5, n = lane & 31;
    int g = wave * 2 + h;
    if (g >= B_ * NA_) return;
    int b = g / NA_, a = g - b * NA_;

    const int* st = starts + b * (NA_ + 1);
    int p0 = st[a], p1 = st[a + 1];
    int seg = p1 - p0;
    int oseg = __shfl_xor(seg, 32);
    int mseg = (seg > oseg) ? seg : oseg;   // wave-uniform
    int segc = (seg > 0) ? seg - 1 : 0;

    const unsigned short* Rb = R + (size_t)b * NM_ * NMAX_;
    const uint2* rcb = rec8 + (size_t)b * NM_;
    const float* csb = csn2 + (size_t)b * NA_ * NMAX_;

    // lane-owned rec8: lane L holds pair p0 + (L&31) (clamped)
    int rmax = (seg > 0) ? (p1 - 1) : ((p0 < NM_) ? p0 : NM_ - 1);
    int ri = p0 + n;
    if (ri > rmax) ri = rmax;
    uint2 rv = rcb[ri];
    int rux = (int)rv.x, ruy = (int)rv.y;

    // R window: 32 independent coalesced ushort loads (gated by mseg)
    unsigned short r[32];
#define LDR(k) { int pk = p0 + (((k) < seg) ? (k) : segc);                   \
                 if (pk >= NM_) pk = NM_ - 1;                                \
                 r[(k)] = Rb[(size_t)pk * NMAX_ + n]; }
    LDR(0) LDR(1) LDR(2) LDR(3) LDR(4) LDR(5) LDR(6) LDR(7)
    if (mseg > 8)  { LDR(8) LDR(9) LDR(10) LDR(11) LDR(12) LDR(13) LDR(14) LDR(15) }
    else { r[8]=r[9]=r[10]=r[11]=r[12]=r[13]=r[14]=r[15]=0; }
    if (mseg > 16) { LDR(16) LDR(17) LDR(18) LDR(19) LDR(20) LDR(21) LDR(22) LDR(23) }
    else { r[16]=r[17]=r[18]=r[19]=r[20]=r[21]=r[22]=r[23]=0; }
    if (mseg > 24) { LDR(24) LDR(25) LDR(26) LDR(27) LDR(28) LDR(29) LDR(30) LDR(31) }
    else { r[24]=r[25]=r[26]=r[27]=r[28]=r[29]=r[30]=r[31]=0; }
#undef LDR

    float sp0 = spp[n], sp1 = spp[32 + n], sp2 = spp[64 + n], sp3 = spp[96 + n];

    const float* opb = op + (size_t)PASS * 2 * NMAX_ * NO_;
    float W0[NO_], W1[NO_];
#pragma unroll
    for (int o = 0; o < NO_; ++o) {
        W0[o] = opb[(0 * NMAX_ + n) * NO_ + o];
        W1[o] = opb[(1 * NMAX_ + n) * NO_ + o];
    }

    int hb = lane & 32;

    // (PASS1) csn2 gathers, upfront, gated
    float cj[32];
    if constexpr (PASS == 1) {
#define LC(k) { int kc_ = ((k) < seg) ? (k) : segc;                          \
                int uy_ = __shfl(ruy, hb + kc_);                             \
                int j_ = ((unsigned)uy_ >> 16) & 0x3fff;                     \
                cj[(k)] = csb[(size_t)j_ * NMAX_ + n]; }
        LC(0) LC(1) LC(2) LC(3) LC(4) LC(5) LC(6) LC(7)
        if (mseg > 8)  { LC(8) LC(9) LC(10) LC(11) LC(12) LC(13) LC(14) LC(15) }
        else { cj[8]=cj[9]=cj[10]=cj[11]=cj[12]=cj[13]=cj[14]=cj[15]=0.f; }
        if (mseg > 16) { LC(16) LC(17) LC(18) LC(19) LC(20) LC(21) LC(22) LC(23) }
        else { cj[16]=cj[17]=cj[18]=cj[19]=cj[20]=cj[21]=cj[22]=cj[23]=0.f; }
        if (mseg > 24) { LC(24) LC(25) LC(26) LC(27) LC(28) LC(29) LC(30) LC(31) }
        else { cj[24]=cj[25]=cj[26]=cj[27]=cj[28]=cj[29]=cj[30]=cj[31]=0.f; }
#undef LC
    }

    float acc0 = 0.f, acc1 = 0.f, acc2 = 0.f, acc3 = 0.f;

#define KK(k) {                                                              \
    int ux_ = __shfl(rux, hb + (k));                                         \
    int uy_ = __shfl(ruy, hb + (k));                                         \
    float xk_ = __half2float(__ushort_as_half((unsigned short)(ux_ & 0xffff)));\
    float yk_ = __half2float(__ushort_as_half((unsigned short)((unsigned)ux_ >> 16)));\
    float zk_ = __half2float(__ushort_as_half((unsigned short)(uy_ & 0xffff)));\
    float rf_ = __half2float(__ushort_as_half(r[(k)]));                      \
    float coef_;                                                             \
    if constexpr (PASS == 0) {                                               \
        int jat_ = ((unsigned)uy_ >> 30) & 3;                                \
        float cjv_ = (jat_ & 2) ? ((jat_ & 1) ? sp3 : sp2)                   \
                                : ((jat_ & 1) ? sp1 : sp0);                  \
        coef_ = rf_ * cjv_;                                                  \
    } else {                                                                 \
        coef_ = rf_ * cj[(k)];                                               \
    }                                                                        \
    coef_ = ((k) < seg) ? coef_ : 0.f;                                       \
    acc0 += coef_;                                                           \
    acc1 = fmaf(coef_, xk_, acc1);                                           \
    acc2 = fmaf(coef_, yk_, acc2);                                           \
    acc3 = fmaf(coef_, zk_, acc3);                                           \
}
#define KK4(k0) if (mseg > (k0)) { KK(k0) KK((k0)+1) KK((k0)+2) KK((k0)+3) }
    KK4(0) KK4(4) KK4(8) KK4(12) KK4(16) KK4(20) KK4(24) KK4(28)
#undef KK4
#undef KK

    // rare tail: segments longer than 32 pairs
    for (int p = p0 + 32; p < p1; ++p) {
        uint2 t = rcb[p];
        float rf = __half2float(__ushort_as_half(Rb[(size_t)p * NMAX_ + n]));
        float xk = __half2float(__ushort_as_half((unsigned short)(t.x & 0xffff)));
        float yk = __half2float(__ushort_as_half((unsigned short)(t.x >> 16)));
        float zk = __half2float(__ushort_as_half((unsigned short)(t.y & 0xffff)));
        float coef;
        if constexpr (PASS == 0) {
            int jat = (t.y >> 30) & 3;
            float cjv = (jat & 2) ? ((jat & 1) ? sp3 : sp2)
                                  : ((jat & 1) ? sp1 : sp0);
            coef = rf * cjv;
        } else {
            int j = (t.y >> 16) & 0x3fff;
            coef = rf * csb[(size_t)j * NMAX_ + n];
        }
        acc0 += coef;
        acc1 = fmaf(coef, xk, acc1);
        acc2 = fmaf(coef, yk, acc2);
        acc3 = fmaf(coef, zk, acc3);
    }

    // t[l][o] butterfly over the 32-lane half (each half = its own atom)
    float t[4][NO_];
#pragma unroll
    for (int o = 0; o < NO_; ++o) {
        t[0][o] = W0[o] * acc0;
        t[1][o] = W1[o] * acc1;
        t[2][o] = W1[o] * acc2;
        t[3][o] = W1[o] * acc3;
    }
#pragma unroll
    for (int off = 1; off < 32; off <<= 1) {
#pragma unroll
        for (int l = 0; l < 4; ++l)
#pragma unroll
            for (int o = 0; o < NO_; ++o)
                t[l][o] += __shfl_xor(t[l][o], off);
    }
    float rho[NO_];
#pragma unroll
    for (int o = 0; o < NO_; ++o)
        rho[o] = t[0][o] * t[0][o] + t[1][o] * t[1][o] +
                 t[2][o] * t[2][o] + t[3][o] * t[3][o];

    if constexpr (PASS == 1) {
        if (n == 0) {
            *reinterpret_cast<float4*>(out + (size_t)g * NO_) =
                make_float4(rho[0], rho[1], rho[2], rho[3]);
        }
    } else {
        // MLP: rho(4) -> h1(4,tanh) -> h2(38,tanh) -> 32, per atom-half
        float h1v[H1_];
#pragma unroll
        for (int k = 0; k < H1_; ++k) {
            float s = b1[k];
#pragma unroll
            for (int o = 0; o < NO_; ++o) s = fmaf(rho[o], w1[o * H1_ + k], s);
            h1v[k] = tanhf(s);
        }
        float sa = b2[n];
        int jbi = 32 + (n < 6 ? n : 5);
        float sb = b2[jbi];
#pragma unroll
        for (int k = 0; k < H1_; ++k) {
            sa = fmaf(h1v[k], w2[k * H2_ + n], sa);
            sb = fmaf(h1v[k], w2[k * H2_ + jbi], sb);
        }
        float hva = tanhf(sa);
        float hvb = tanhf(sb);
        float on = b3[n];
#pragma unroll
        for (int j2 = 0; j2 < 32; ++j2) {
            float hj = __shfl(hva, hb + j2);
            on = fmaf(hj, w3[j2 * NMAX_ + n], on);
        }
#pragma unroll
        for (int j2 = 0; j2 < 6; ++j2) {
            float hj = __shfl(hvb, hb + j2);
            on = fmaf(hj, w3[(32 + j2) * NMAX_ + n], on);
        }
        int aat = sorted_numbers[a];
        float basev = (aat & 2) ? ((aat & 1) ? sp3 : sp2)
                                : ((aat & 1) ? sp1 : sp0);
        csn2[(size_t)g * NMAX_ + n] = basev + on;
    }
}

// ---------------------------------------------------------------------------
// Fallback pass kernel (round-2 proven) — used if ws_size too small.
// ---------------------------------------------------------------------------
template <int PASS>
__global__ __launch_bounds__(256) void fb_pass_kernel(
    const float* __restrict__ disp, const float* __restrict__ alpha,
    const float* __restrict__ rsp, const float* __restrict__ spp,
    const float* __restrict__ op, const float* __restrict__ w1,
    const float* __restrict__ b1, const float* __restrict__ w2,
    const float* __restrict__ b2, const float* __restrict__ w3,
    const float* __restrict__ b3, const int* __restrict__ jidx,
    const int* __restrict__ sorted_numbers, const int* __restrict__ starts,
    float* __restrict__ csn2, float* __restrict__ out)
{
    int wave = blockIdx.x * 4 + (threadIdx.x >> 6);
    int lane = threadIdx.x & 63;
    int h = lane >> 5;
    int n = lane & 31;
    int g = wave * 2 + h;
    if (g >= B_ * NA_) return;
    int b = g / NA_, a = g - b * NA_;

    float al[NS_], rvv[NS_], spv[NS_];
#pragma unroll
    for (int s = 0; s < NS_; ++s) {
        al[s] = alpha[s * NMAX_ + n];
        rvv[s] = rsp[s * NMAX_ + n];
        spv[s] = spp[s * NMAX_ + n];
    }
    const float* opb = op + (size_t)PASS * 2 * NMAX_ * NO_;
    float W0[NO_], W1[NO_];
#pragma unroll
    for (int o = 0; o < NO_; ++o) {
        W0[o] = opb[(0 * NMAX_ + n) * NO_ + o];
        W1[o] = opb[(1 * NMAX_ + n) * NO_ + o];
    }
    const int* st = starts + b * (NA_ + 1);
    int p0 = st[a], p1 = st[a + 1];
    const int* jjb = jidx + (size_t)b * NM_;
    const float* dpb = disp + (size_t)b * NM_ * 3;
    const float* csb = csn2 + (size_t)b * NA_ * NMAX_;

    float acc0 = 0.f, acc1 = 0.f, acc2 = 0.f, acc3 = 0.f;
    for (int p = p0; p < p1; ++p) {
        int j = jjb[p];
        float x = dpb[p * 3 + 0], y = dpb[p * 3 + 1], z = dpb[p * 3 + 2];
        float dist = sqrtf(x * x + y * y + z * z);
        float c = __cosf(dist * (PI_F / 6.0f));
        float fcv = 0.25f * (c + 1.f) * (c + 1.f);
        int jat = sorted_numbers[j];
        bool s0 = (jat & 1) != 0, s1 = (jat & 2) != 0;
        float av = s1 ? (s0 ? al[3] : al[2]) : (s0 ? al[1] : al[0]);
        float rsv = s1 ? (s0 ? rvv[3] : rvv[2]) : (s0 ? rvv[1] : rvv[0]);
        float cjv;
        if constexpr (PASS == 0)
            cjv = s1 ? (s0 ? spv[3] : spv[2]) : (s0 ? spv[1] : spv[0]);
        else
            cjv = csb[(size_t)j * NMAX_ + n];
        float dd = dist - rsv;
        float coef = fcv * cjv * __expf(av * dd * dd);
        acc0 += coef;
        acc1 = fmaf(coef, x, acc1);
        acc2 = fmaf(coef, y, acc2);
        acc3 = fmaf(coef, z, acc3);
    }
    float t[4][NO_];
#pragma unroll
    for (int o = 0; o < NO_; ++o) {
        t[0][o] = W0[o] * acc0; t[1][o] = W1[o] * acc1;
        t[2][o] = W1[o] * acc2; t[3][o] = W1[o] * acc3;
    }
#pragma unroll
    for (int off = 1; off < 32; off <<= 1) {
#pragma unroll
        for (int l = 0; l < 4; ++l)
#pragma unroll
            for (int o = 0; o < NO_; ++o)
                t[l][o] += __shfl_xor(t[l][o], off);
    }
    float rho[NO_];
#pragma unroll
    for (int o = 0; o < NO_; ++o)
        rho[o] = t[0][o] * t[0][o] + t[1][o] * t[1][o] +
                 t[2][o] * t[2][o] + t[3][o] * t[3][o];
    if constexpr (PASS == 1) {
        if (n == 0)
            *reinterpret_cast<float4*>(out + (size_t)g * NO_) =
                make_float4(rho[0], rho[1], rho[2], rho[3]);
    } else {
        float h1v[H1_];
#pragma unroll
        for (int k = 0; k < H1_; ++k) {
            float s = b1[k];
#pragma unroll
            for (int o = 0; o < NO_; ++o) s = fmaf(rho[o], w1[o * H1_ + k], s);
            h1v[k] = tanhf(s);
        }
        float sa = b2[n];
        int jbi = 32 + (n < 6 ? n : 5);
        float sb = b2[jbi];
#pragma unroll
        for (int k = 0; k < H1_; ++k) {
            sa = fmaf(h1v[k], w2[k * H2_ + n], sa);
            sb = fmaf(h1v[k], w2[k * H2_ + jbi], sb);
        }
        float hva = tanhf(sa), hvb = tanhf(sb);
        float on = b3[n];
        int base_lane = h << 5;
#pragma unroll
        for (int j2 = 0; j2 < 32; ++j2)
            on = fmaf(__shfl(hva, base_lane + j2), w3[j2 * NMAX_ + n], on);
#pragma unroll
        for (int j2 = 0; j2 < 6; ++j2)
            on = fmaf(__shfl(hvb, base_lane + j2), w3[(32 + j2) * NMAX_ + n], on);
        int aat = sorted_numbers[a];
        bool t0b = (aat & 1) != 0, t1b = (aat & 2) != 0;
        float basev = t1b ? (t0b ? spv[3] : spv[2]) : (t0b ? spv[1] : spv[0]);
        csn2[(size_t)g * NMAX_ + n] = basev + on;
    }
}

extern "C" void kernel_launch(void* const* d_in, const int* in_sizes, int n_in,
                              void* d_out, int out_size, void* d_ws, size_t ws_size,
                              hipStream_t stream) {
    const float* disp = (const float*)d_in[0];
    const float* alpha = (const float*)d_in[1];
    const float* rsp = (const float*)d_in[2];
    const float* spp = (const float*)d_in[3];
    const float* op = (const float*)d_in[4];
    const float* w1 = (const float*)d_in[5];
    const float* b1 = (const float*)d_in[6];
    const float* w2 = (const float*)d_in[7];
    const float* b2 = (const float*)d_in[8];
    const float* w3 = (const float*)d_in[9];
    const float* b3 = (const float*)d_in[10];
    const int* iidx = (const int*)d_in[11];
    const int* jidx = (const int*)d_in[12];
    const int* sn = (const int*)d_in[13];
    float* out = (float*)d_out;

    int nthr = B_ * NM_;

    if (ws_size >= WS_NEED) {
        float* csn2 = (float*)((char*)d_ws + CSN_OFF);
        uint2* rec8 = (uint2*)((char*)d_ws + REC_OFF);
        unsigned short* R = (unsigned short*)((char*)d_ws + R_OFF);
        int* starts = (int*)((char*)d_ws + ST_OFF);

        starts_kernel<<<(nthr + 255) / 256, 256, 0, stream>>>(iidx, starts);
        int pblocks = (B_ * NM_ / PPT_) / 8;   // 2 halves/wave, 4 waves/block
        prep0_kernel<<<pblocks, 256, 0, stream>>>(disp, alpha, rsp, jidx, sn, R, rec8);
        int ablocks = (B_ * NA_) / 8;          // 2 atoms/wave, 4 waves/block
        pass_kernel<0><<<ablocks, 256, 0, stream>>>(R, rec8, spp, op, w1, b1, w2,
                                                    b2, w3, b3, sn, starts, csn2, out);
        pass_kernel<1><<<ablocks, 256, 0, stream>>>(R, rec8, spp, op, w1, b1, w2,
                                                    b2, w3, b3, sn, starts, csn2, out);
    } else {
        float* csn2 = (float*)d_ws;
        int* starts = (int*)((char*)d_ws + CSN_BYTES);
        int nblocks = ((B_ * NA_) / 2 + 3) / 4;
        starts_kernel<<<(nthr + 255) / 256, 256, 0, stream>>>(iidx, starts);
        fb_pass_kernel<0><<<nblocks, 256, 0, stream>>>(disp, alpha, rsp, spp, op,
                                                       w1, b1, w2, b2, w3, b3,
                                                       jidx, sn, starts, csn2, out);
        fb_pass_kernel<1><<<nblocks, 256, 0, stream>>>(disp, alpha, rsp, spp, op,
                                                       w1, b1, w2, b2, w3, b3,
                                                       jidx, sn, starts, csn2, out);
    }
}

// Round 8
// 104.630 us; speedup vs baseline: 1.1122x; 1.1122x over previous
//
#include <hip/hip_runtime.h>
#include <hip/hip_fp16.h>
#include <math.h>

#define NA_ 10000
#define NM_ 150000
#define B_  4
#define NS_ 4
#define NMAX_ 32
#define NO_ 4
#define H1_ 4
#define H2_ 38
#define PPT_ 8
#define PI_F 3.14159265358979323846f

// ---- ws layout (main path) ----
#define CSN_OFF   ((size_t)0)
#define CSN_BYTES ((size_t)B_ * NA_ * NMAX_ * 4)            // 5,120,000
#define REC_OFF   (CSN_OFF + CSN_BYTES)
#define REC_BYTES (((size_t)B_ * NM_ + 32) * 16)            // float4 rec + slack
#define R_OFF     (REC_OFF + REC_BYTES)
#define R_BYTES   (((size_t)B_ * NM_ + 64) * NMAX_ * 2)     // row-major R + slack
#define ST_OFF    (R_OFF + R_BYTES + 128)
#define ST_BYTES  ((size_t)B_ * (NA_ + 1) * 4 + 16)
#define WS_NEED   (ST_OFF + ST_BYTES)

// ---------------------------------------------------------------------------
// Kernel 0: segment starts from sorted iidx.
// ---------------------------------------------------------------------------
__global__ void starts_kernel(const int* __restrict__ iidx, int* __restrict__ starts) {
    int p = blockIdx.x * blockDim.x + threadIdx.x;
    if (p >= B_ * NM_) return;
    int b = p / NM_, pl = p - b * NM_;
    const int* ii = iidx + (size_t)b * NM_;
    int* st = starts + (size_t)b * (NA_ + 1);
    int cur = ii[pl];
    int prev = (pl == 0) ? -1 : ii[pl - 1];
    for (int a = prev + 1; a <= cur; ++a) st[a] = pl;
    if (pl == NM_ - 1) {
        for (int a = cur + 1; a <= NA_; ++a) st[a] = NM_;
    }
}

// ---------------------------------------------------------------------------
// prep0: pair-parallel (half-wave = 32 lanes = n; PPT_ consecutive pairs).
// Writes row-major R[b][p][n] (64B coalesced rows, fp16) and
// rec16[p] = float4(x, y, z, bitcast(j | jat<<14)).
// ---------------------------------------------------------------------------
__global__ __launch_bounds__(256) void prep0_kernel(
    const float* __restrict__ disp, const float* __restrict__ alpha,
    const float* __restrict__ rsp, const int* __restrict__ jidx,
    const int* __restrict__ sorted_numbers,
    unsigned short* __restrict__ R, float4* __restrict__ rec16)
{
    int wid = (blockIdx.x * 256 + threadIdx.x) >> 6;
    int lane = threadIdx.x & 63;
    int h = lane >> 5, n = lane & 31;
    int gh = wid * 2 + h;                    // [0, B*NM/PPT)
    constexpr int HPI = NM_ / PPT_;
    int b = gh / HPI;
    int pbase = (gh - b * HPI) * PPT_;

    float al0 = alpha[n],      al1 = alpha[32 + n];
    float al2 = alpha[64 + n], al3 = alpha[96 + n];
    float rv0 = rsp[n],        rv1 = rsp[32 + n];
    float rv2 = rsp[64 + n],   rv3 = rsp[96 + n];

    const int* jjb = jidx + (size_t)b * NM_;
    const float* dpb = disp + (size_t)b * NM_ * 3;
    unsigned short* Rb = R + (size_t)b * NM_ * NMAX_;
    float4* rcb = rec16 + (size_t)b * NM_;

#pragma unroll
    for (int k = 0; k < PPT_; ++k) {
        int p = pbase + k;
        int j = jjb[p];
        float x = dpb[p * 3 + 0];
        float y = dpb[p * 3 + 1];
        float z = dpb[p * 3 + 2];
        int jat = sorted_numbers[j];
        float dist = sqrtf(x * x + y * y + z * z);
        float c = __cosf(dist * (PI_F / 6.0f));
        float fc = 0.25f * (c + 1.f) * (c + 1.f);
        bool s0 = (jat & 1) != 0, s1 = (jat & 2) != 0;
        float av = s1 ? (s0 ? al3 : al2) : (s0 ? al1 : al0);
        float rv = s1 ? (s0 ? rv3 : rv2) : (s0 ? rv1 : rv0);
        float dd = dist - rv;
        Rb[(size_t)p * NMAX_ + n] =
            __half_as_ushort(__float2half_rn(fc * __expf(av * dd * dd)));
        if (n == k) {
            rcb[p] = make_float4(x, y, z, __int_as_float(j | (jat << 14)));
        }
    }
}

// ---------------------------------------------------------------------------
// pass: one wave = TWO atoms (half-wave each, lane = n).
// Prologue (all independent, truly upfront thanks to 128-VGPR budget):
//   - stage rec16[p0..p0+31] into this wave's LDS slice (1 vload + 1 ds_write)
//   - 32 coalesced ushort R loads via base + immediate offsets (slack-padded)
//   - (PASS1) 32 csn2 gathers, j sourced from LDS dword reads
// Compute: static 32-pair unroll, gated by wave-uniform mseg every 8; per
// pair ONE uniform ds_read_b128 (hw broadcast) + 5-7 VALU. seg>32 -> tail.
// ---------------------------------------------------------------------------
template <int PASS>
__global__ __launch_bounds__(256, 4) void pass_kernel(
    const unsigned short* __restrict__ R, const float4* __restrict__ rec16,
    const float* __restrict__ spp, const float* __restrict__ op,
    const float* __restrict__ w1, const float* __restrict__ b1,
    const float* __restrict__ w2, const float* __restrict__ b2,
    const float* __restrict__ w3, const float* __restrict__ b3,
    const int* __restrict__ sorted_numbers, const int* __restrict__ starts,
    float* __restrict__ csn2, float* __restrict__ out)
{
    __shared__ float4 lds_rec[4][2][32];
    int wv = threadIdx.x >> 6;
    int wave = blockIdx.x * 4 + wv;
    int lane = threadIdx.x & 63;
    int h = lane >> 5, n = lane & 31;
    int g = wave * 2 + h;
    if (g >= B_ * NA_) return;
    int b = g / NA_, a = g - b * NA_;

    const int* st = starts + b * (NA_ + 1);
    int p0 = st[a], p1 = st[a + 1];
    int seg = p1 - p0;
    int oseg = __shfl_xor(seg, 32);
    int mseg = (seg > oseg) ? seg : oseg;   // wave-uniform

    const float4* rcb = rec16 + (size_t)b * NM_;
    const float* csb = csn2 + (size_t)b * NA_ * NMAX_;

    // stage this atom's 32 rec entries into LDS (slack-safe past p1/NM)
    lds_rec[wv][h][n] = rcb[p0 + n];
    const float4* lp = &lds_rec[wv][h][0];
    const int* lpi = (const int*)lp;

    // R window: 32 coalesced ushort loads, base + immediate offset
    const unsigned short* Rbase = R + (size_t)b * NM_ * NMAX_ + (size_t)p0 * NMAX_ + n;
    unsigned short r[32];
#define LDR(k) r[(k)] = Rbase[(k) * NMAX_];
#define LDR8(k0) LDR(k0) LDR((k0)+1) LDR((k0)+2) LDR((k0)+3) \
                 LDR((k0)+4) LDR((k0)+5) LDR((k0)+6) LDR((k0)+7)
    LDR8(0)
    if (mseg > 8)  { LDR8(8) }  else { r[8]=r[9]=r[10]=r[11]=r[12]=r[13]=r[14]=r[15]=0; }
    if (mseg > 16) { LDR8(16) } else { r[16]=r[17]=r[18]=r[19]=r[20]=r[21]=r[22]=r[23]=0; }
    if (mseg > 24) { LDR8(24) } else { r[24]=r[25]=r[26]=r[27]=r[28]=r[29]=r[30]=r[31]=0; }
#undef LDR8
#undef LDR

    float sp0 = spp[n], sp1 = spp[32 + n], sp2 = spp[64 + n], sp3 = spp[96 + n];

    const float* opb = op + (size_t)PASS * 2 * NMAX_ * NO_;
    float W0[NO_], W1[NO_];
#pragma unroll
    for (int o = 0; o < NO_; ++o) {
        W0[o] = opb[(0 * NMAX_ + n) * NO_ + o];
        W1[o] = opb[(1 * NMAX_ + n) * NO_ + o];
    }

    // (PASS1) upfront csn2 gathers; j from LDS dwords (garbage past seg is
    // masked later; addresses stay inside the workspace).
    float cj[32];
    if constexpr (PASS == 1) {
#define LC(k) { int j_ = lpi[(k) * 4 + 3] & 0x3fff;                          \
                cj[(k)] = csb[(size_t)j_ * NMAX_ + n]; }
#define LC8(k0) LC(k0) LC((k0)+1) LC((k0)+2) LC((k0)+3) \
                LC((k0)+4) LC((k0)+5) LC((k0)+6) LC((k0)+7)
        LC8(0)
        if (mseg > 8)  { LC8(8) }  else { cj[8]=cj[9]=cj[10]=cj[11]=cj[12]=cj[13]=cj[14]=cj[15]=0.f; }
        if (mseg > 16) { LC8(16) } else { cj[16]=cj[17]=cj[18]=cj[19]=cj[20]=cj[21]=cj[22]=cj[23]=0.f; }
        if (mseg > 24) { LC8(24) } else { cj[24]=cj[25]=cj[26]=cj[27]=cj[28]=cj[29]=cj[30]=cj[31]=0.f; }
#undef LC8
#undef LC
    }

    float acc0 = 0.f, acc1 = 0.f, acc2 = 0.f, acc3 = 0.f;

#define KK(k) {                                                              \
    float4 q_ = lp[(k)];                          /* uniform ds_read_b128 */ \
    float rf_ = __half2float(__ushort_as_half(r[(k)]));                      \
    float coef_;                                                             \
    if constexpr (PASS == 0) {                                               \
        int w_ = __float_as_int(q_.w);                                       \
        int jat_ = (w_ >> 14) & 3;                                           \
        float cjv_ = (jat_ & 2) ? ((jat_ & 1) ? sp3 : sp2)                   \
                                : ((jat_ & 1) ? sp1 : sp0);                  \
        coef_ = rf_ * cjv_;                                                  \
    } else {                                                                 \
        coef_ = rf_ * cj[(k)];                                               \
    }                                                                        \
    coef_ = ((k) < seg) ? coef_ : 0.f;                                       \
    acc0 += coef_;                                                           \
    acc1 = fmaf(coef_, q_.x, acc1);                                          \
    acc2 = fmaf(coef_, q_.y, acc2);                                          \
    acc3 = fmaf(coef_, q_.z, acc3);                                          \
}
#define KK8(k0) if (mseg > (k0)) { KK(k0) KK((k0)+1) KK((k0)+2) KK((k0)+3)   \
                                   KK((k0)+4) KK((k0)+5) KK((k0)+6) KK((k0)+7) }
    KK8(0) KK8(8) KK8(16) KK8(24)
#undef KK8
#undef KK

    // rare tail: segments longer than 32 pairs (global reads, inline gathers)
    for (int p = p0 + 32; p < p1; ++p) {
        float4 t = rcb[p];
        float rf = __half2float(__ushort_as_half(
            R[(size_t)b * NM_ * NMAX_ + (size_t)p * NMAX_ + n]));
        int w = __float_as_int(t.w);
        float coef;
        if constexpr (PASS == 0) {
            int jat = (w >> 14) & 3;
            float cjv = (jat & 2) ? ((jat & 1) ? sp3 : sp2)
                                  : ((jat & 1) ? sp1 : sp0);
            coef = rf * cjv;
        } else {
            coef = rf * csb[(size_t)(w & 0x3fff) * NMAX_ + n];
        }
        acc0 += coef;
        acc1 = fmaf(coef, t.x, acc1);
        acc2 = fmaf(coef, t.y, acc2);
        acc3 = fmaf(coef, t.z, acc3);
    }

    // t[l][o] butterfly over the 32-lane half (each half = its own atom)
    float t[4][NO_];
#pragma unroll
    for (int o = 0; o < NO_; ++o) {
        t[0][o] = W0[o] * acc0;
        t[1][o] = W1[o] * acc1;
        t[2][o] = W1[o] * acc2;
        t[3][o] = W1[o] * acc3;
    }
#pragma unroll
    for (int off = 1; off < 32; off <<= 1) {
#pragma unroll
        for (int l = 0; l < 4; ++l)
#pragma unroll
            for (int o = 0; o < NO_; ++o)
                t[l][o] += __shfl_xor(t[l][o], off);
    }
    float rho[NO_];
#pragma unroll
    for (int o = 0; o < NO_; ++o)
        rho[o] = t[0][o] * t[0][o] + t[1][o] * t[1][o] +
                 t[2][o] * t[2][o] + t[3][o] * t[3][o];

    int hb = lane & 32;

    if constexpr (PASS == 1) {
        if (n == 0) {
            *reinterpret_cast<float4*>(out + (size_t)g * NO_) =
                make_float4(rho[0], rho[1], rho[2], rho[3]);
        }
    } else {
        // MLP: rho(4) -> h1(4,tanh) -> h2(38,tanh) -> 32, per atom-half
        float h1v[H1_];
#pragma unroll
        for (int k = 0; k < H1_; ++k) {
            float s = b1[k];
#pragma unroll
            for (int o = 0; o < NO_; ++o) s = fmaf(rho[o], w1[o * H1_ + k], s);
            h1v[k] = tanhf(s);
        }
        float sa = b2[n];
        int jbi = 32 + (n < 6 ? n : 5);
        float sb = b2[jbi];
#pragma unroll
        for (int k = 0; k < H1_; ++k) {
            sa = fmaf(h1v[k], w2[k * H2_ + n], sa);
            sb = fmaf(h1v[k], w2[k * H2_ + jbi], sb);
        }
        float hva = tanhf(sa);
        float hvb = tanhf(sb);
        float on = b3[n];
#pragma unroll
        for (int j2 = 0; j2 < 32; ++j2) {
            float hj = __shfl(hva, hb + j2);
            on = fmaf(hj, w3[j2 * NMAX_ + n], on);
        }
#pragma unroll
        for (int j2 = 0; j2 < 6; ++j2) {
            float hj = __shfl(hvb, hb + j2);
            on = fmaf(hj, w3[(32 + j2) * NMAX_ + n], on);
        }
        int aat = sorted_numbers[a];
        float basev = (aat & 2) ? ((aat & 1) ? sp3 : sp2)
                                : ((aat & 1) ? sp1 : sp0);
        csn2[(size_t)g * NMAX_ + n] = basev + on;
    }
}

// ---------------------------------------------------------------------------
// Fallback pass kernel (round-2 proven) — used if ws_size too small.
// ---------------------------------------------------------------------------
template <int PASS>
__global__ __launch_bounds__(256) void fb_pass_kernel(
    const float* __restrict__ disp, const float* __restrict__ alpha,
    const float* __restrict__ rsp, const float* __restrict__ spp,
    const float* __restrict__ op, const float* __restrict__ w1,
    const float* __restrict__ b1, const float* __restrict__ w2,
    const float* __restrict__ b2, const float* __restrict__ w3,
    const float* __restrict__ b3, const int* __restrict__ jidx,
    const int* __restrict__ sorted_numbers, const int* __restrict__ starts,
    float* __restrict__ csn2, float* __restrict__ out)
{
    int wave = blockIdx.x * 4 + (threadIdx.x >> 6);
    int lane = threadIdx.x & 63;
    int h = lane >> 5;
    int n = lane & 31;
    int g = wave * 2 + h;
    if (g >= B_ * NA_) return;
    int b = g / NA_, a = g - b * NA_;

    float al[NS_], rvv[NS_], spv[NS_];
#pragma unroll
    for (int s = 0; s < NS_; ++s) {
        al[s] = alpha[s * NMAX_ + n];
        rvv[s] = rsp[s * NMAX_ + n];
        spv[s] = spp[s * NMAX_ + n];
    }
    const float* opb = op + (size_t)PASS * 2 * NMAX_ * NO_;
    float W0[NO_], W1[NO_];
#pragma unroll
    for (int o = 0; o < NO_; ++o) {
        W0[o] = opb[(0 * NMAX_ + n) * NO_ + o];
        W1[o] = opb[(1 * NMAX_ + n) * NO_ + o];
    }
    const int* st = starts + b * (NA_ + 1);
    int p0 = st[a], p1 = st[a + 1];
    const int* jjb = jidx + (size_t)b * NM_;
    const float* dpb = disp + (size_t)b * NM_ * 3;
    const float* csb = csn2 + (size_t)b * NA_ * NMAX_;

    float acc0 = 0.f, acc1 = 0.f, acc2 = 0.f, acc3 = 0.f;
    for (int p = p0; p < p1; ++p) {
        int j = jjb[p];
        float x = dpb[p * 3 + 0], y = dpb[p * 3 + 1], z = dpb[p * 3 + 2];
        float dist = sqrtf(x * x + y * y + z * z);
        float c = __cosf(dist * (PI_F / 6.0f));
        float fcv = 0.25f * (c + 1.f) * (c + 1.f);
        int jat = sorted_numbers[j];
        bool s0 = (jat & 1) != 0, s1 = (jat & 2) != 0;
        float av = s1 ? (s0 ? al[3] : al[2]) : (s0 ? al[1] : al[0]);
        float rsv = s1 ? (s0 ? rvv[3] : rvv[2]) : (s0 ? rvv[1] : rvv[0]);
        float cjv;
        if constexpr (PASS == 0)
            cjv = s1 ? (s0 ? spv[3] : spv[2]) : (s0 ? spv[1] : spv[0]);
        else
            cjv = csb[(size_t)j * NMAX_ + n];
        float dd = dist - rsv;
        float coef = fcv * cjv * __expf(av * dd * dd);
        acc0 += coef;
        acc1 = fmaf(coef, x, acc1);
        acc2 = fmaf(coef, y, acc2);
        acc3 = fmaf(coef, z, acc3);
    }
    float t[4][NO_];
#pragma unroll
    for (int o = 0; o < NO_; ++o) {
        t[0][o] = W0[o] * acc0; t[1][o] = W1[o] * acc1;
        t[2][o] = W1[o] * acc2; t[3][o] = W1[o] * acc3;
    }
#pragma unroll
    for (int off = 1; off < 32; off <<= 1) {
#pragma unroll
        for (int l = 0; l < 4; ++l)
#pragma unroll
            for (int o = 0; o < NO_; ++o)
                t[l][o] += __shfl_xor(t[l][o], off);
    }
    float rho[NO_];
#pragma unroll
    for (int o = 0; o < NO_; ++o)
        rho[o] = t[0][o] * t[0][o] + t[1][o] * t[1][o] +
                 t[2][o] * t[2][o] + t[3][o] * t[3][o];
    if constexpr (PASS == 1) {
        if (n == 0)
            *reinterpret_cast<float4*>(out + (size_t)g * NO_) =
                make_float4(rho[0], rho[1], rho[2], rho[3]);
    } else {
        float h1v[H1_];
#pragma unroll
        for (int k = 0; k < H1_; ++k) {
            float s = b1[k];
#pragma unroll
            for (int o = 0; o < NO_; ++o) s = fmaf(rho[o], w1[o * H1_ + k], s);
            h1v[k] = tanhf(s);
        }
        float sa = b2[n];
        int jbi = 32 + (n < 6 ? n : 5);
        float sb = b2[jbi];
#pragma unroll
        for (int k = 0; k < H1_; ++k) {
            sa = fmaf(h1v[k], w2[k * H2_ + n], sa);
            sb = fmaf(h1v[k], w2[k * H2_ + jbi], sb);
        }
        float hva = tanhf(sa), hvb = tanhf(sb);
        float on = b3[n];
        int base_lane = h << 5;
#pragma unroll
        for (int j2 = 0; j2 < 32; ++j2)
            on = fmaf(__shfl(hva, base_lane + j2), w3[j2 * NMAX_ + n], on);
#pragma unroll
        for (int j2 = 0; j2 < 6; ++j2)
            on = fmaf(__shfl(hvb, base_lane + j2), w3[(32 + j2) * NMAX_ + n], on);
        int aat = sorted_numbers[a];
        bool t0b = (aat & 1) != 0, t1b = (aat & 2) != 0;
        float basev = t1b ? (t0b ? spv[3] : spv[2]) : (t0b ? spv[1] : spv[0]);
        csn2[(size_t)g * NMAX_ + n] = basev + on;
    }
}

extern "C" void kernel_launch(void* const* d_in, const int* in_sizes, int n_in,
                              void* d_out, int out_size, void* d_ws, size_t ws_size,
                              hipStream_t stream) {
    const float* disp = (const float*)d_in[0];
    const float* alpha = (const float*)d_in[1];
    const float* rsp = (const float*)d_in[2];
    const float* spp = (const float*)d_in[3];
    const float* op = (const float*)d_in[4];
    const float* w1 = (const float*)d_in[5];
    const float* b1 = (const float*)d_in[6];
    const float* w2 = (const float*)d_in[7];
    const float* b2 = (const float*)d_in[8];
    const float* w3 = (const float*)d_in[9];
    const float* b3 = (const float*)d_in[10];
    const int* iidx = (const int*)d_in[11];
    const int* jidx = (const int*)d_in[12];
    const int* sn = (const int*)d_in[13];
    float* out = (float*)d_out;

    int nthr = B_ * NM_;

    if (ws_size >= WS_NEED) {
        float* csn2 = (float*)((char*)d_ws + CSN_OFF);
        float4* rec16 = (float4*)((char*)d_ws + REC_OFF);
        unsigned short* R = (unsigned short*)((char*)d_ws + R_OFF);
        int* starts = (int*)((char*)d_ws + ST_OFF);

        starts_kernel<<<(nthr + 255) / 256, 256, 0, stream>>>(iidx, starts);
        int pblocks = (B_ * NM_ / PPT_) / 8;   // 2 halves/wave, 4 waves/block
        prep0_kernel<<<pblocks, 256, 0, stream>>>(disp, alpha, rsp, jidx, sn, R, rec16);
        int ablocks = (B_ * NA_) / 8;          // 2 atoms/wave, 4 waves/block
        pass_kernel<0><<<ablocks, 256, 0, stream>>>(R, rec16, spp, op, w1, b1, w2,
                                                    b2, w3, b3, sn, starts, csn2, out);
        pass_kernel<1><<<ablocks, 256, 0, stream>>>(R, rec16, spp, op, w1, b1, w2,
                                                    b2, w3, b3, sn, starts, csn2, out);
    } else {
        float* csn2 = (float*)d_ws;
        int* starts = (int*)((char*)d_ws + CSN_BYTES);
        int nblocks = ((B_ * NA_) / 2 + 3) / 4;
        starts_kernel<<<(nthr + 255) / 256, 256, 0, stream>>>(iidx, starts);
        fb_pass_kernel<0><<<nblocks, 256, 0, stream>>>(disp, alpha, rsp, spp, op,
                                                       w1, b1, w2, b2, w3, b3,
                                                       jidx, sn, starts, csn2, out);
        fb_pass_kernel<1><<<nblocks, 256, 0, stream>>>(disp, alpha, rsp, spp, op,
                                                       w1, b1, w2, b2, w3, b3,
                                                       jidx, sn, starts, csn2, out);
    }
}

// Round 9
// 102.479 us; speedup vs baseline: 1.1356x; 1.0210x over previous
//
#include <hip/hip_runtime.h>
#include <hip/hip_fp16.h>
#include <math.h>

#define NA_ 10000
#define NM_ 150000
#define B_  4
#define NS_ 4
#define NMAX_ 32
#define NO_ 4
#define H1_ 4
#define H2_ 38
#define PPT_ 8
#define PI_F 3.14159265358979323846f

// ---- ws layout (main path) ----
#define CSN_OFF   ((size_t)0)
#define CSN_BYTES ((size_t)B_ * NA_ * NMAX_ * 4)            // 5,120,000
#define REC_OFF   (CSN_OFF + CSN_BYTES)
#define REC_BYTES (((size_t)B_ * NM_ + 32) * 16)            // float4 rec + slack
#define R_OFF     (REC_OFF + REC_BYTES)
#define R_BYTES   (((size_t)B_ * NM_ + 64) * NMAX_ * 2)     // row-major R + slack
#define ST_OFF    (R_OFF + R_BYTES + 128)
#define ST_BYTES  ((size_t)B_ * (NA_ + 1) * 4 + 16)
#define WS_NEED   (ST_OFF + ST_BYTES)

// ---------------------------------------------------------------------------
// Kernel 0: segment starts from sorted iidx.
// ---------------------------------------------------------------------------
__global__ void starts_kernel(const int* __restrict__ iidx, int* __restrict__ starts) {
    int p = blockIdx.x * blockDim.x + threadIdx.x;
    if (p >= B_ * NM_) return;
    int b = p / NM_, pl = p - b * NM_;
    const int* ii = iidx + (size_t)b * NM_;
    int* st = starts + (size_t)b * (NA_ + 1);
    int cur = ii[pl];
    int prev = (pl == 0) ? -1 : ii[pl - 1];
    for (int a = prev + 1; a <= cur; ++a) st[a] = pl;
    if (pl == NM_ - 1) {
        for (int a = cur + 1; a <= NA_; ++a) st[a] = NM_;
    }
}

// ---------------------------------------------------------------------------
// prep0: pair-parallel (half-wave = 32 lanes = n; PPT_ consecutive pairs).
// BATCHED PHASES to hide gather latency:
//   phase 1: 8 independent j loads
//   phase 2: 8 independent sorted_numbers[j] gathers + 24 xyz loads
//   phase 3: compute + store (R rows coalesced; rec16 from lane k)
// Writes row-major R[b][p][n] (fp16) and rec16[p]=(x,y,z, j|jat<<14).
// ---------------------------------------------------------------------------
__global__ __launch_bounds__(256) void prep0_kernel(
    const float* __restrict__ disp, const float* __restrict__ alpha,
    const float* __restrict__ rsp, const int* __restrict__ jidx,
    const int* __restrict__ sorted_numbers,
    unsigned short* __restrict__ R, float4* __restrict__ rec16)
{
    int wid = (blockIdx.x * 256 + threadIdx.x) >> 6;
    int lane = threadIdx.x & 63;
    int h = lane >> 5, n = lane & 31;
    int gh = wid * 2 + h;                    // [0, B*NM/PPT)
    constexpr int HPI = NM_ / PPT_;
    int b = gh / HPI;
    int pbase = (gh - b * HPI) * PPT_;

    float al0 = alpha[n],      al1 = alpha[32 + n];
    float al2 = alpha[64 + n], al3 = alpha[96 + n];
    float rv0 = rsp[n],        rv1 = rsp[32 + n];
    float rv2 = rsp[64 + n],   rv3 = rsp[96 + n];

    const int* jjb = jidx + (size_t)b * NM_;
    const float* dpb = disp + (size_t)b * NM_ * 3;
    unsigned short* Rb = R + (size_t)b * NM_ * NMAX_;
    float4* rcb = rec16 + (size_t)b * NM_;

    // phase 1: independent j loads
    int jv[PPT_];
#pragma unroll
    for (int k = 0; k < PPT_; ++k) jv[k] = jjb[pbase + k];

    // phase 2: independent jat gathers + xyz loads
    int jat[PPT_];
    float xv[PPT_], yv[PPT_], zv[PPT_];
#pragma unroll
    for (int k = 0; k < PPT_; ++k) jat[k] = sorted_numbers[jv[k]];
#pragma unroll
    for (int k = 0; k < PPT_; ++k) {
        xv[k] = dpb[(pbase + k) * 3 + 0];
        yv[k] = dpb[(pbase + k) * 3 + 1];
        zv[k] = dpb[(pbase + k) * 3 + 2];
    }

    // phase 3: compute + store
#pragma unroll
    for (int k = 0; k < PPT_; ++k) {
        int p = pbase + k;
        float x = xv[k], y = yv[k], z = zv[k];
        float dist = sqrtf(x * x + y * y + z * z);
        float c = __cosf(dist * (PI_F / 6.0f));
        float fc = 0.25f * (c + 1.f) * (c + 1.f);
        int jt = jat[k];
        bool s0 = (jt & 1) != 0, s1 = (jt & 2) != 0;
        float av = s1 ? (s0 ? al3 : al2) : (s0 ? al1 : al0);
        float rv = s1 ? (s0 ? rv3 : rv2) : (s0 ? rv1 : rv0);
        float dd = dist - rv;
        Rb[(size_t)p * NMAX_ + n] =
            __half_as_ushort(__float2half_rn(fc * __expf(av * dd * dd)));
        if (n == k) {
            rcb[p] = make_float4(x, y, z, __int_as_float(jv[k] | (jt << 14)));
        }
    }
}

// ---------------------------------------------------------------------------
// pass: one wave = TWO atoms (half-wave each, lane = n).
// Prologue (all independent, truly upfront thanks to 128-VGPR budget):
//   - stage rec16[p0..p0+31] into this wave's LDS slice (1 vload + 1 ds_write)
//   - 32 coalesced ushort R loads via base + immediate offsets (slack-padded)
//   - (PASS1) 32 csn2 gathers, j sourced from LDS dword reads
// Compute: static 32-pair unroll, gated by wave-uniform mseg every 8; per
// pair ONE uniform ds_read_b128 (hw broadcast) + 5-7 VALU. seg>32 -> tail.
// ---------------------------------------------------------------------------
template <int PASS>
__global__ __launch_bounds__(256, 4) void pass_kernel(
    const unsigned short* __restrict__ R, const float4* __restrict__ rec16,
    const float* __restrict__ spp, const float* __restrict__ op,
    const float* __restrict__ w1, const float* __restrict__ b1,
    const float* __restrict__ w2, const float* __restrict__ b2,
    const float* __restrict__ w3, const float* __restrict__ b3,
    const int* __restrict__ sorted_numbers, const int* __restrict__ starts,
    float* __restrict__ csn2, float* __restrict__ out)
{
    __shared__ float4 lds_rec[4][2][32];
    int wv = threadIdx.x >> 6;
    int wave = blockIdx.x * 4 + wv;
    int lane = threadIdx.x & 63;
    int h = lane >> 5, n = lane & 31;
    int g = wave * 2 + h;
    if (g >= B_ * NA_) return;
    int b = g / NA_, a = g - b * NA_;

    const int* st = starts + b * (NA_ + 1);
    int p0 = st[a], p1 = st[a + 1];
    int seg = p1 - p0;
    int oseg = __shfl_xor(seg, 32);
    int mseg = (seg > oseg) ? seg : oseg;   // wave-uniform

    const float4* rcb = rec16 + (size_t)b * NM_;
    const float* csb = csn2 + (size_t)b * NA_ * NMAX_;

    // stage this atom's 32 rec entries into LDS (slack-safe past p1/NM)
    lds_rec[wv][h][n] = rcb[p0 + n];
    const float4* lp = &lds_rec[wv][h][0];
    const int* lpi = (const int*)lp;

    // R window: 32 coalesced ushort loads, base + immediate offset
    const unsigned short* Rbase = R + (size_t)b * NM_ * NMAX_ + (size_t)p0 * NMAX_ + n;
    unsigned short r[32];
#define LDR(k) r[(k)] = Rbase[(k) * NMAX_];
#define LDR8(k0) LDR(k0) LDR((k0)+1) LDR((k0)+2) LDR((k0)+3) \
                 LDR((k0)+4) LDR((k0)+5) LDR((k0)+6) LDR((k0)+7)
    LDR8(0)
    if (mseg > 8)  { LDR8(8) }  else { r[8]=r[9]=r[10]=r[11]=r[12]=r[13]=r[14]=r[15]=0; }
    if (mseg > 16) { LDR8(16) } else { r[16]=r[17]=r[18]=r[19]=r[20]=r[21]=r[22]=r[23]=0; }
    if (mseg > 24) { LDR8(24) } else { r[24]=r[25]=r[26]=r[27]=r[28]=r[29]=r[30]=r[31]=0; }
#undef LDR8
#undef LDR

    float sp0 = spp[n], sp1 = spp[32 + n], sp2 = spp[64 + n], sp3 = spp[96 + n];

    const float* opb = op + (size_t)PASS * 2 * NMAX_ * NO_;
    float W0[NO_], W1[NO_];
#pragma unroll
    for (int o = 0; o < NO_; ++o) {
        W0[o] = opb[(0 * NMAX_ + n) * NO_ + o];
        W1[o] = opb[(1 * NMAX_ + n) * NO_ + o];
    }

    // (PASS1) upfront csn2 gathers; j from LDS dwords (garbage past seg is
    // masked later; addresses stay inside the workspace).
    float cj[32];
    if constexpr (PASS == 1) {
#define LC(k) { int j_ = lpi[(k) * 4 + 3] & 0x3fff;                          \
                cj[(k)] = csb[(size_t)j_ * NMAX_ + n]; }
#define LC8(k0) LC(k0) LC((k0)+1) LC((k0)+2) LC((k0)+3) \
                LC((k0)+4) LC((k0)+5) LC((k0)+6) LC((k0)+7)
        LC8(0)
        if (mseg > 8)  { LC8(8) }  else { cj[8]=cj[9]=cj[10]=cj[11]=cj[12]=cj[13]=cj[14]=cj[15]=0.f; }
        if (mseg > 16) { LC8(16) } else { cj[16]=cj[17]=cj[18]=cj[19]=cj[20]=cj[21]=cj[22]=cj[23]=0.f; }
        if (mseg > 24) { LC8(24) } else { cj[24]=cj[25]=cj[26]=cj[27]=cj[28]=cj[29]=cj[30]=cj[31]=0.f; }
#undef LC8
#undef LC
    }

    float acc0 = 0.f, acc1 = 0.f, acc2 = 0.f, acc3 = 0.f;

#define KK(k) {                                                              \
    float4 q_ = lp[(k)];                          /* uniform ds_read_b128 */ \
    float rf_ = __half2float(__ushort_as_half(r[(k)]));                      \
    float coef_;                                                             \
    if constexpr (PASS == 0) {                                               \
        int w_ = __float_as_int(q_.w);                                       \
        int jat_ = (w_ >> 14) & 3;                                           \
        float cjv_ = (jat_ & 2) ? ((jat_ & 1) ? sp3 : sp2)                   \
                                : ((jat_ & 1) ? sp1 : sp0);                  \
        coef_ = rf_ * cjv_;                                                  \
    } else {                                                                 \
        coef_ = rf_ * cj[(k)];                                               \
    }                                                                        \
    coef_ = ((k) < seg) ? coef_ : 0.f;                                       \
    acc0 += coef_;                                                           \
    acc1 = fmaf(coef_, q_.x, acc1);                                          \
    acc2 = fmaf(coef_, q_.y, acc2);                                          \
    acc3 = fmaf(coef_, q_.z, acc3);                                          \
}
#define KK8(k0) if (mseg > (k0)) { KK(k0) KK((k0)+1) KK((k0)+2) KK((k0)+3)   \
                                   KK((k0)+4) KK((k0)+5) KK((k0)+6) KK((k0)+7) }
    KK8(0) KK8(8) KK8(16) KK8(24)
#undef KK8
#undef KK

    // rare tail: segments longer than 32 pairs (global reads, inline gathers)
    for (int p = p0 + 32; p < p1; ++p) {
        float4 t = rcb[p];
        float rf = __half2float(__ushort_as_half(
            R[(size_t)b * NM_ * NMAX_ + (size_t)p * NMAX_ + n]));
        int w = __float_as_int(t.w);
        float coef;
        if constexpr (PASS == 0) {
            int jat = (w >> 14) & 3;
            float cjv = (jat & 2) ? ((jat & 1) ? sp3 : sp2)
                                  : ((jat & 1) ? sp1 : sp0);
            coef = rf * cjv;
        } else {
            coef = rf * csb[(size_t)(w & 0x3fff) * NMAX_ + n];
        }
        acc0 += coef;
        acc1 = fmaf(coef, t.x, acc1);
        acc2 = fmaf(coef, t.y, acc2);
        acc3 = fmaf(coef, t.z, acc3);
    }

    // t[l][o] butterfly over the 32-lane half (each half = its own atom)
    float t[4][NO_];
#pragma unroll
    for (int o = 0; o < NO_; ++o) {
        t[0][o] = W0[o] * acc0;
        t[1][o] = W1[o] * acc1;
        t[2][o] = W1[o] * acc2;
        t[3][o] = W1[o] * acc3;
    }
#pragma unroll
    for (int off = 1; off < 32; off <<= 1) {
#pragma unroll
        for (int l = 0; l < 4; ++l)
#pragma unroll
            for (int o = 0; o < NO_; ++o)
                t[l][o] += __shfl_xor(t[l][o], off);
    }
    float rho[NO_];
#pragma unroll
    for (int o = 0; o < NO_; ++o)
        rho[o] = t[0][o] * t[0][o] + t[1][o] * t[1][o] +
                 t[2][o] * t[2][o] + t[3][o] * t[3][o];

    int hb = lane & 32;

    if constexpr (PASS == 1) {
        if (n == 0) {
            *reinterpret_cast<float4*>(out + (size_t)g * NO_) =
                make_float4(rho[0], rho[1], rho[2], rho[3]);
        }
    } else {
        // MLP: rho(4) -> h1(4,tanh) -> h2(38,tanh) -> 32, per atom-half
        float h1v[H1_];
#pragma unroll
        for (int k = 0; k < H1_; ++k) {
            float s = b1[k];
#pragma unroll
            for (int o = 0; o < NO_; ++o) s = fmaf(rho[o], w1[o * H1_ + k], s);
            h1v[k] = tanhf(s);
        }
        float sa = b2[n];
        int jbi = 32 + (n < 6 ? n : 5);
        float sb = b2[jbi];
#pragma unroll
        for (int k = 0; k < H1_; ++k) {
            sa = fmaf(h1v[k], w2[k * H2_ + n], sa);
            sb = fmaf(h1v[k], w2[k * H2_ + jbi], sb);
        }
        float hva = tanhf(sa);
        float hvb = tanhf(sb);
        float on = b3[n];
#pragma unroll
        for (int j2 = 0; j2 < 32; ++j2) {
            float hj = __shfl(hva, hb + j2);
            on = fmaf(hj, w3[j2 * NMAX_ + n], on);
        }
#pragma unroll
        for (int j2 = 0; j2 < 6; ++j2) {
            float hj = __shfl(hvb, hb + j2);
            on = fmaf(hj, w3[(32 + j2) * NMAX_ + n], on);
        }
        int aat = sorted_numbers[a];
        float basev = (aat & 2) ? ((aat & 1) ? sp3 : sp2)
                                : ((aat & 1) ? sp1 : sp0);
        csn2[(size_t)g * NMAX_ + n] = basev + on;
    }
}

// ---------------------------------------------------------------------------
// Fallback pass kernel (round-2 proven) — used if ws_size too small.
// ---------------------------------------------------------------------------
template <int PASS>
__global__ __launch_bounds__(256) void fb_pass_kernel(
    const float* __restrict__ disp, const float* __restrict__ alpha,
    const float* __restrict__ rsp, const float* __restrict__ spp,
    const float* __restrict__ op, const float* __restrict__ w1,
    const float* __restrict__ b1, const float* __restrict__ w2,
    const float* __restrict__ b2, const float* __restrict__ w3,
    const float* __restrict__ b3, const int* __restrict__ jidx,
    const int* __restrict__ sorted_numbers, const int* __restrict__ starts,
    float* __restrict__ csn2, float* __restrict__ out)
{
    int wave = blockIdx.x * 4 + (threadIdx.x >> 6);
    int lane = threadIdx.x & 63;
    int h = lane >> 5;
    int n = lane & 31;
    int g = wave * 2 + h;
    if (g >= B_ * NA_) return;
    int b = g / NA_, a = g - b * NA_;

    float al[NS_], rvv[NS_], spv[NS_];
#pragma unroll
    for (int s = 0; s < NS_; ++s) {
        al[s] = alpha[s * NMAX_ + n];
        rvv[s] = rsp[s * NMAX_ + n];
        spv[s] = spp[s * NMAX_ + n];
    }
    const float* opb = op + (size_t)PASS * 2 * NMAX_ * NO_;
    float W0[NO_], W1[NO_];
#pragma unroll
    for (int o = 0; o < NO_; ++o) {
        W0[o] = opb[(0 * NMAX_ + n) * NO_ + o];
        W1[o] = opb[(1 * NMAX_ + n) * NO_ + o];
    }
    const int* st = starts + b * (NA_ + 1);
    int p0 = st[a], p1 = st[a + 1];
    const int* jjb = jidx + (size_t)b * NM_;
    const float* dpb = disp + (size_t)b * NM_ * 3;
    const float* csb = csn2 + (size_t)b * NA_ * NMAX_;

    float acc0 = 0.f, acc1 = 0.f, acc2 = 0.f, acc3 = 0.f;
    for (int p = p0; p < p1; ++p) {
        int j = jjb[p];
        float x = dpb[p * 3 + 0], y = dpb[p * 3 + 1], z = dpb[p * 3 + 2];
        float dist = sqrtf(x * x + y * y + z * z);
        float c = __cosf(dist * (PI_F / 6.0f));
        float fcv = 0.25f * (c + 1.f) * (c + 1.f);
        int jat = sorted_numbers[j];
        bool s0 = (jat & 1) != 0, s1 = (jat & 2) != 0;
        float av = s1 ? (s0 ? al[3] : al[2]) : (s0 ? al[1] : al[0]);
        float rsv = s1 ? (s0 ? rvv[3] : rvv[2]) : (s0 ? rvv[1] : rvv[0]);
        float cjv;
        if constexpr (PASS == 0)
            cjv = s1 ? (s0 ? spv[3] : spv[2]) : (s0 ? spv[1] : spv[0]);
        else
            cjv = csb[(size_t)j * NMAX_ + n];
        float dd = dist - rsv;
        float coef = fcv * cjv * __expf(av * dd * dd);
        acc0 += coef;
        acc1 = fmaf(coef, x, acc1);
        acc2 = fmaf(coef, y, acc2);
        acc3 = fmaf(coef, z, acc3);
    }
    float t[4][NO_];
#pragma unroll
    for (int o = 0; o < NO_; ++o) {
        t[0][o] = W0[o] * acc0; t[1][o] = W1[o] * acc1;
        t[2][o] = W1[o] * acc2; t[3][o] = W1[o] * acc3;
    }
#pragma unroll
    for (int off = 1; off < 32; off <<= 1) {
#pragma unroll
        for (int l = 0; l < 4; ++l)
#pragma unroll
            for (int o = 0; o < NO_; ++o)
                t[l][o] += __shfl_xor(t[l][o], off);
    }
    float rho[NO_];
#pragma unroll
    for (int o = 0; o < NO_; ++o)
        rho[o] = t[0][o] * t[0][o] + t[1][o] * t[1][o] +
                 t[2][o] * t[2][o] + t[3][o] * t[3][o];
    if constexpr (PASS == 1) {
        if (n == 0)
            *reinterpret_cast<float4*>(out + (size_t)g * NO_) =
                make_float4(rho[0], rho[1], rho[2], rho[3]);
    } else {
        float h1v[H1_];
#pragma unroll
        for (int k = 0; k < H1_; ++k) {
            float s = b1[k];
#pragma unroll
            for (int o = 0; o < NO_; ++o) s = fmaf(rho[o], w1[o * H1_ + k], s);
            h1v[k] = tanhf(s);
        }
        float sa = b2[n];
        int jbi = 32 + (n < 6 ? n : 5);
        float sb = b2[jbi];
#pragma unroll
        for (int k = 0; k < H1_; ++k) {
            sa = fmaf(h1v[k], w2[k * H2_ + n], sa);
            sb = fmaf(h1v[k], w2[k * H2_ + jbi], sb);
        }
        float hva = tanhf(sa), hvb = tanhf(sb);
        float on = b3[n];
        int base_lane = h << 5;
#pragma unroll
        for (int j2 = 0; j2 < 32; ++j2)
            on = fmaf(__shfl(hva, base_lane + j2), w3[j2 * NMAX_ + n], on);
#pragma unroll
        for (int j2 = 0; j2 < 6; ++j2)
            on = fmaf(__shfl(hvb, base_lane + j2), w3[(32 + j2) * NMAX_ + n], on);
        int aat = sorted_numbers[a];
        bool t0b = (aat & 1) != 0, t1b = (aat & 2) != 0;
        float basev = t1b ? (t0b ? spv[3] : spv[2]) : (t0b ? spv[1] : spv[0]);
        csn2[(size_t)g * NMAX_ + n] = basev + on;
    }
}

extern "C" void kernel_launch(void* const* d_in, const int* in_sizes, int n_in,
                              void* d_out, int out_size, void* d_ws, size_t ws_size,
                              hipStream_t stream) {
    const float* disp = (const float*)d_in[0];
    const float* alpha = (const float*)d_in[1];
    const float* rsp = (const float*)d_in[2];
    const float* spp = (const float*)d_in[3];
    const float* op = (const float*)d_in[4];
    const float* w1 = (const float*)d_in[5];
    const float* b1 = (const float*)d_in[6];
    const float* w2 = (const float*)d_in[7];
    const float* b2 = (const float*)d_in[8];
    const float* w3 = (const float*)d_in[9];
    const float* b3 = (const float*)d_in[10];
    const int* iidx = (const int*)d_in[11];
    const int* jidx = (const int*)d_in[12];
    const int* sn = (const int*)d_in[13];
    float* out = (float*)d_out;

    int nthr = B_ * NM_;

    if (ws_size >= WS_NEED) {
        float* csn2 = (float*)((char*)d_ws + CSN_OFF);
        float4* rec16 = (float4*)((char*)d_ws + REC_OFF);
        unsigned short* R = (unsigned short*)((char*)d_ws + R_OFF);
        int* starts = (int*)((char*)d_ws + ST_OFF);

        starts_kernel<<<(nthr + 255) / 256, 256, 0, stream>>>(iidx, starts);
        int pblocks = (B_ * NM_ / PPT_) / 8;   // 2 halves/wave, 4 waves/block
        prep0_kernel<<<pblocks, 256, 0, stream>>>(disp, alpha, rsp, jidx, sn, R, rec16);
        int ablocks = (B_ * NA_) / 8;          // 2 atoms/wave, 4 waves/block
        pass_kernel<0><<<ablocks, 256, 0, stream>>>(R, rec16, spp, op, w1, b1, w2,
                                                    b2, w3, b3, sn, starts, csn2, out);
        pass_kernel<1><<<ablocks, 256, 0, stream>>>(R, rec16, spp, op, w1, b1, w2,
                                                    b2, w3, b3, sn, starts, csn2, out);
    } else {
        float* csn2 = (float*)d_ws;
        int* starts = (int*)((char*)d_ws + CSN_BYTES);
        int nblocks = ((B_ * NA_) / 2 + 3) / 4;
        starts_kernel<<<(nthr + 255) / 256, 256, 0, stream>>>(iidx, starts);
        fb_pass_kernel<0><<<nblocks, 256, 0, stream>>>(disp, alpha, rsp, spp, op,
                                                       w1, b1, w2, b2, w3, b3,
                                                       jidx, sn, starts, csn2, out);
        fb_pass_kernel<1><<<nblocks, 256, 0, stream>>>(disp, alpha, rsp, spp, op,
                                                       w1, b1, w2, b2, w3, b3,
                                                       jidx, sn, starts, csn2, out);
    }
}

// Round 10
// 78.810 us; speedup vs baseline: 1.4766x; 1.3003x over previous
//
#include <hip/hip_runtime.h>
#include <math.h>

#define NA_ 10000
#define NM_ 150000
#define B_  4
#define NS_ 4
#define NMAX_ 32
#define NO_ 4
#define H1_ 4
#define H2_ 38
#define PI_F 3.14159265358979323846f

// ---- ws layout ----
#define CSN_OFF   ((size_t)0)
#define CSN_BYTES ((size_t)B_ * NA_ * NMAX_ * 4)            // 5,120,000
#define ST_OFF    (CSN_OFF + CSN_BYTES)

// ---------------------------------------------------------------------------
// Kernel 0: segment starts from sorted iidx.
// ---------------------------------------------------------------------------
__global__ void starts_kernel(const int* __restrict__ iidx, int* __restrict__ starts) {
    int p = blockIdx.x * blockDim.x + threadIdx.x;
    if (p >= B_ * NM_) return;
    int b = p / NM_, pl = p - b * NM_;
    const int* ii = iidx + (size_t)b * NM_;
    int* st = starts + (size_t)b * (NA_ + 1);
    int cur = ii[pl];
    int prev = (pl == 0) ? -1 : ii[pl - 1];
    for (int a = prev + 1; a <= cur; ++a) st[a] = pl;
    if (pl == NM_ - 1) {
        for (int a = cur + 1; a <= NA_; ++a) st[a] = NM_;
    }
}

// ---------------------------------------------------------------------------
// pass: one wave = TWO atoms (half-wave each, lane = n). FUSED: no prep, no R.
// Stage (per half, lane n owns pair p0+n):
//   j (coalesced) -> jat gather (L2 40KB table) ; xyz (coalesced)
//   dist, fcut computed ONCE per pair (per lane)
//   LDS: rec = (fc*x, fc*y, fc*z, j|jat<<14) ; df = (dist, fc)
// Compute: static 32-pair unroll gated every 8 by wave-uniform mseg. Per
// (pair,n): uniform ds_read_b128+b64 broadcast, alpha/rs cndmask select,
// 1 exp, ~5 fma. (PASS1) csn2 row-gathers issued upfront. seg>32 -> tail.
// PASS=0 epilogue: MLP -> csn2. PASS=1: rho -> out.
// ---------------------------------------------------------------------------
template <int PASS>
__global__ __launch_bounds__(256, 4) void pass_kernel(
    const float* __restrict__ disp, const int* __restrict__ jidx,
    const float* __restrict__ alpha, const float* __restrict__ rsp,
    const float* __restrict__ spp, const float* __restrict__ op,
    const float* __restrict__ w1, const float* __restrict__ b1,
    const float* __restrict__ w2, const float* __restrict__ b2,
    const float* __restrict__ w3, const float* __restrict__ b3,
    const int* __restrict__ sorted_numbers, const int* __restrict__ starts,
    float* __restrict__ csn2, float* __restrict__ out)
{
    __shared__ float4 lds_rec[4][2][32];
    __shared__ float2 lds_df[4][2][32];
    int wv = threadIdx.x >> 6;
    int wave = blockIdx.x * 4 + wv;
    int lane = threadIdx.x & 63;
    int h = lane >> 5, n = lane & 31;
    int g = wave * 2 + h;
    if (g >= B_ * NA_) return;
    int b = g / NA_, a = g - b * NA_;

    const int* st = starts + b * (NA_ + 1);
    int p0 = st[a], p1 = st[a + 1];
    int seg = p1 - p0;
    int oseg = __shfl_xor(seg, 32);
    int mseg = (seg > oseg) ? seg : oseg;   // wave-uniform

    const int* jjb = jidx + (size_t)b * NM_;
    const float* dpb = disp + (size_t)b * NM_ * 3;
    const float* csb = csn2 + (size_t)b * NA_ * NMAX_;

    // ---- stage: lane n handles pair p0+n (clamped in-image) ----
    int pk = p0 + n;
    if (pk > NM_ - 1) pk = NM_ - 1;
    int jmine = jjb[pk];
    float sx = dpb[pk * 3 + 0];
    float sy = dpb[pk * 3 + 1];
    float sz = dpb[pk * 3 + 2];
    int jatm = sorted_numbers[jmine];
    float sd = sqrtf(sx * sx + sy * sy + sz * sz);
    float sc = __cosf(sd * (PI_F / 6.0f));
    float sfc = 0.25f * (sc + 1.f) * (sc + 1.f);
    lds_rec[wv][h][n] = make_float4(sfc * sx, sfc * sy, sfc * sz,
                                    __int_as_float(jmine | (jatm << 14)));
    lds_df[wv][h][n] = make_float2(sd, sfc);
    const float4* lp = &lds_rec[wv][h][0];
    const float2* ldf = &lds_df[wv][h][0];
    const int* lpi = (const int*)lp;

    // per-n tables in registers
    float al0 = alpha[n],      al1 = alpha[32 + n];
    float al2 = alpha[64 + n], al3 = alpha[96 + n];
    float rv0 = rsp[n],        rv1 = rsp[32 + n];
    float rv2 = rsp[64 + n],   rv3 = rsp[96 + n];
    float sp0 = spp[n], sp1 = spp[32 + n], sp2 = spp[64 + n], sp3 = spp[96 + n];

    const float* opb = op + (size_t)PASS * 2 * NMAX_ * NO_;
    float W0[NO_], W1[NO_];
#pragma unroll
    for (int o = 0; o < NO_; ++o) {
        W0[o] = opb[(0 * NMAX_ + n) * NO_ + o];
        W1[o] = opb[(1 * NMAX_ + n) * NO_ + o];
    }

    // (PASS1) upfront csn2 gathers; j from LDS dwords (invalid -> masked later)
    float cj[32];
    if constexpr (PASS == 1) {
#define LC(k) { int j_ = lpi[(k) * 4 + 3] & 0x3fff;                          \
                cj[(k)] = csb[(size_t)j_ * NMAX_ + n]; }
#define LC8(k0) LC(k0) LC((k0)+1) LC((k0)+2) LC((k0)+3) \
                LC((k0)+4) LC((k0)+5) LC((k0)+6) LC((k0)+7)
        LC8(0)
        if (mseg > 8)  { LC8(8) }  else { cj[8]=cj[9]=cj[10]=cj[11]=cj[12]=cj[13]=cj[14]=cj[15]=0.f; }
        if (mseg > 16) { LC8(16) } else { cj[16]=cj[17]=cj[18]=cj[19]=cj[20]=cj[21]=cj[22]=cj[23]=0.f; }
        if (mseg > 24) { LC8(24) } else { cj[24]=cj[25]=cj[26]=cj[27]=cj[28]=cj[29]=cj[30]=cj[31]=0.f; }
#undef LC8
#undef LC
    }

    float acc0 = 0.f, acc1 = 0.f, acc2 = 0.f, acc3 = 0.f;

#define KK(k) {                                                              \
    float4 q_ = lp[(k)];                 /* uniform ds_read_b128 bcast */    \
    float2 df_ = ldf[(k)];               /* uniform ds_read_b64 bcast  */    \
    int w_ = __float_as_int(q_.w);                                           \
    bool s0_ = (w_ & (1 << 14)) != 0;                                        \
    bool s1_ = (w_ & (1 << 15)) != 0;                                        \
    float av_ = s1_ ? (s0_ ? al3 : al2) : (s0_ ? al1 : al0);                 \
    float rv_ = s1_ ? (s0_ ? rv3 : rv2) : (s0_ ? rv1 : rv0);                 \
    float dd_ = df_.x - rv_;                                                 \
    float e_ = __expf(av_ * dd_ * dd_);                                      \
    float cv_;                                                               \
    if constexpr (PASS == 0) {                                               \
        cv_ = s1_ ? (s0_ ? sp3 : sp2) : (s0_ ? sp1 : sp0);                   \
    } else {                                                                 \
        cv_ = cj[(k)];                                                       \
    }                                                                        \
    float coef_ = e_ * cv_;                                                  \
    coef_ = ((k) < seg) ? coef_ : 0.f;                                       \
    acc0 = fmaf(coef_, df_.y, acc0);                                         \
    acc1 = fmaf(coef_, q_.x, acc1);                                          \
    acc2 = fmaf(coef_, q_.y, acc2);                                          \
    acc3 = fmaf(coef_, q_.z, acc3);                                          \
}
#define KK8(k0) if (mseg > (k0)) { KK(k0) KK((k0)+1) KK((k0)+2) KK((k0)+3)   \
                                   KK((k0)+4) KK((k0)+5) KK((k0)+6) KK((k0)+7) }
    KK8(0) KK8(8) KK8(16) KK8(24)
#undef KK8
#undef KK

    // rare tail: segments longer than 32 pairs (raw per-pair gather+compute)
    for (int p = p0 + 32; p < p1; ++p) {
        int j = jjb[p];
        float x = dpb[p * 3 + 0], y = dpb[p * 3 + 1], z = dpb[p * 3 + 2];
        int jat = sorted_numbers[j];
        float dist = sqrtf(x * x + y * y + z * z);
        float c = __cosf(dist * (PI_F / 6.0f));
        float fc = 0.25f * (c + 1.f) * (c + 1.f);
        bool s0 = (jat & 1) != 0, s1 = (jat & 2) != 0;
        float av = s1 ? (s0 ? al3 : al2) : (s0 ? al1 : al0);
        float rv = s1 ? (s0 ? rv3 : rv2) : (s0 ? rv1 : rv0);
        float dd = dist - rv;
        float e = __expf(av * dd * dd);
        float cv;
        if constexpr (PASS == 0)
            cv = s1 ? (s0 ? sp3 : sp2) : (s0 ? sp1 : sp0);
        else
            cv = csb[(size_t)j * NMAX_ + n];
        float coef = fc * e * cv;
        acc0 += coef;
        acc1 = fmaf(coef, x, acc1);
        acc2 = fmaf(coef, y, acc2);
        acc3 = fmaf(coef, z, acc3);
    }

    // t[l][o] butterfly over the 32-lane half (each half = its own atom)
    float t[4][NO_];
#pragma unroll
    for (int o = 0; o < NO_; ++o) {
        t[0][o] = W0[o] * acc0;
        t[1][o] = W1[o] * acc1;
        t[2][o] = W1[o] * acc2;
        t[3][o] = W1[o] * acc3;
    }
#pragma unroll
    for (int off = 1; off < 32; off <<= 1) {
#pragma unroll
        for (int l = 0; l < 4; ++l)
#pragma unroll
            for (int o = 0; o < NO_; ++o)
                t[l][o] += __shfl_xor(t[l][o], off);
    }
    float rho[NO_];
#pragma unroll
    for (int o = 0; o < NO_; ++o)
        rho[o] = t[0][o] * t[0][o] + t[1][o] * t[1][o] +
                 t[2][o] * t[2][o] + t[3][o] * t[3][o];

    int hb = lane & 32;

    if constexpr (PASS == 1) {
        if (n == 0) {
            *reinterpret_cast<float4*>(out + (size_t)g * NO_) =
                make_float4(rho[0], rho[1], rho[2], rho[3]);
        }
    } else {
        // MLP: rho(4) -> h1(4,tanh) -> h2(38,tanh) -> 32, per atom-half
        float h1v[H1_];
#pragma unroll
        for (int k = 0; k < H1_; ++k) {
            float s = b1[k];
#pragma unroll
            for (int o = 0; o < NO_; ++o) s = fmaf(rho[o], w1[o * H1_ + k], s);
            h1v[k] = tanhf(s);
        }
        float sa = b2[n];
        int jbi = 32 + (n < 6 ? n : 5);
        float sb = b2[jbi];
#pragma unroll
        for (int k = 0; k < H1_; ++k) {
            sa = fmaf(h1v[k], w2[k * H2_ + n], sa);
            sb = fmaf(h1v[k], w2[k * H2_ + jbi], sb);
        }
        float hva = tanhf(sa);
        float hvb = tanhf(sb);
        float on = b3[n];
#pragma unroll
        for (int j2 = 0; j2 < 32; ++j2) {
            float hj = __shfl(hva, hb + j2);
            on = fmaf(hj, w3[j2 * NMAX_ + n], on);
        }
#pragma unroll
        for (int j2 = 0; j2 < 6; ++j2) {
            float hj = __shfl(hvb, hb + j2);
            on = fmaf(hj, w3[(32 + j2) * NMAX_ + n], on);
        }
        int aat = sorted_numbers[a];
        float basev = (aat & 2) ? ((aat & 1) ? sp3 : sp2)
                                : ((aat & 1) ? sp1 : sp0);
        csn2[(size_t)g * NMAX_ + n] = basev + on;
    }
}

extern "C" void kernel_launch(void* const* d_in, const int* in_sizes, int n_in,
                              void* d_out, int out_size, void* d_ws, size_t ws_size,
                              hipStream_t stream) {
    const float* disp = (const float*)d_in[0];
    const float* alpha = (const float*)d_in[1];
    const float* rsp = (const float*)d_in[2];
    const float* spp = (const float*)d_in[3];
    const float* op = (const float*)d_in[4];
    const float* w1 = (const float*)d_in[5];
    const float* b1 = (const float*)d_in[6];
    const float* w2 = (const float*)d_in[7];
    const float* b2 = (const float*)d_in[8];
    const float* w3 = (const float*)d_in[9];
    const float* b3 = (const float*)d_in[10];
    const int* iidx = (const int*)d_in[11];
    const int* jidx = (const int*)d_in[12];
    const int* sn = (const int*)d_in[13];
    float* out = (float*)d_out;

    float* csn2 = (float*)((char*)d_ws + CSN_OFF);
    int* starts = (int*)((char*)d_ws + ST_OFF);

    int nthr = B_ * NM_;
    starts_kernel<<<(nthr + 255) / 256, 256, 0, stream>>>(iidx, starts);

    int ablocks = (B_ * NA_) / 8;          // 2 atoms/wave, 4 waves/block
    pass_kernel<0><<<ablocks, 256, 0, stream>>>(disp, jidx, alpha, rsp, spp, op,
                                                w1, b1, w2, b2, w3, b3, sn,
                                                starts, csn2, out);
    pass_kernel<1><<<ablocks, 256, 0, stream>>>(disp, jidx, alpha, rsp, spp, op,
                                                w1, b1, w2, b2, w3, b3, sn,
                                                starts, csn2, out);
}

// Round 12
// 76.473 us; speedup vs baseline: 1.5217x; 1.0306x over previous
//
#include <hip/hip_runtime.h>
#include <hip/hip_fp16.h>
#include <math.h>

#define NA_ 10000
#define NM_ 150000
#define B_  4
#define NS_ 4
#define NMAX_ 32
#define NO_ 4
#define H1_ 4
#define H2_ 38
#define PI_F 3.14159265358979323846f

// ---- ws layout ----
#define CSN_OFF   ((size_t)0)
#define CSN_BYTES ((size_t)B_ * NA_ * NMAX_ * 4)            // 5,120,000
#define ST_OFF    (CSN_OFF + CSN_BYTES)
#define ST_BYTES  ((size_t)B_ * (NA_ + 1) * 4 + 64)
#define E_OFF     (ST_OFF + ST_BYTES)
#define E_BYTES   (((size_t)B_ * NM_ + 64) * NMAX_ * 2)     // fp16 E + slack
#define WS_NEED_E (E_OFF + E_BYTES)

__device__ __forceinline__ float fast_tanh(float x) {
    float t = __expf(2.0f * x);
    return 1.0f - __fdividef(2.0f, t + 1.0f);
}

// ---------------------------------------------------------------------------
// Kernel 0: segment starts from sorted iidx.
// ---------------------------------------------------------------------------
__global__ void starts_kernel(const int* __restrict__ iidx, int* __restrict__ starts) {
    int p = blockIdx.x * blockDim.x + threadIdx.x;
    if (p >= B_ * NM_) return;
    int b = p / NM_, pl = p - b * NM_;
    const int* ii = iidx + (size_t)b * NM_;
    int* st = starts + (size_t)b * (NA_ + 1);
    int cur = ii[pl];
    int prev = (pl == 0) ? -1 : ii[pl - 1];
    for (int a = prev + 1; a <= cur; ++a) st[a] = pl;
    if (pl == NM_ - 1) {
        for (int a = cur + 1; a <= NA_; ++a) st[a] = NM_;
    }
}

// ---------------------------------------------------------------------------
// pass: one wave = TWO atoms (half-wave each, lane = n).
// PASS0 (and fallback PASS1 !USE_E): fused radial compute, raw xyz in LDS,
//   (dist,fc) in LDS; per-4 mseg-gated static unroll; PASS0+USE_E stores
//   E=fc*exp(...) fp16 (exec-guarded k<seg: each pair written by its owner).
// PASS1 USE_E: light staging (j+xyz only), 32 coalesced E ushort loads +
//   32 csn2 gathers upfront, KK = cvt*cj + 4 fma. No exp, no selects.
// Epilogue: butterfly reduce -> rho; PASS0: fast-tanh MLP -> csn2; PASS1: out.
// ---------------------------------------------------------------------------
template <int PASS, int USE_E>
__global__ __launch_bounds__(256, 4) void pass_kernel(
    const float* __restrict__ disp, const int* __restrict__ jidx,
    const float* __restrict__ alpha, const float* __restrict__ rsp,
    const float* __restrict__ spp, const float* __restrict__ op,
    const float* __restrict__ w1, const float* __restrict__ b1,
    const float* __restrict__ w2, const float* __restrict__ b2,
    const float* __restrict__ w3, const float* __restrict__ b3,
    const int* __restrict__ sorted_numbers, const int* __restrict__ starts,
    float* __restrict__ csn2, unsigned short* __restrict__ E,
    float* __restrict__ out)
{
    __shared__ float4 lds_rec[4][2][32];
    __shared__ float2 lds_df[4][2][32];
    int wv = threadIdx.x >> 6;
    int wave = blockIdx.x * 4 + wv;
    int lane = threadIdx.x & 63;
    int h = lane >> 5, n = lane & 31;
    int g = wave * 2 + h;
    if (g >= B_ * NA_) return;
    int b = g / NA_, a = g - b * NA_;

    const int* st = starts + b * (NA_ + 1);
    int p0 = st[a], p1 = st[a + 1];
    int seg = p1 - p0;
    int oseg = __shfl_xor(seg, 32);
    int mseg = (seg > oseg) ? seg : oseg;   // wave-uniform

    const int* jjb = jidx + (size_t)b * NM_;
    const float* dpb = disp + (size_t)b * NM_ * 3;
    const float* csb = csn2 + (size_t)b * NA_ * NMAX_;

    // ---- stage: lane n handles pair p0+n (clamped in-image) ----
    int pk = p0 + n;
    if (pk > NM_ - 1) pk = NM_ - 1;
    int jmine = jjb[pk];
    float sx = dpb[pk * 3 + 0];
    float sy = dpb[pk * 3 + 1];
    float sz = dpb[pk * 3 + 2];
    if constexpr (PASS == 0 || !USE_E) {
        int jatm = sorted_numbers[jmine];
        float sd = sqrtf(sx * sx + sy * sy + sz * sz);
        float sc = __cosf(sd * (PI_F / 6.0f));
        float sfc = 0.25f * (sc + 1.f) * (sc + 1.f);
        lds_rec[wv][h][n] = make_float4(sx, sy, sz,
                                        __int_as_float(jmine | (jatm << 14)));
        lds_df[wv][h][n] = make_float2(sd, sfc);
    } else {
        lds_rec[wv][h][n] = make_float4(sx, sy, sz, __int_as_float(jmine));
    }
    const float4* lp = &lds_rec[wv][h][0];
    const float2* ldf = &lds_df[wv][h][0];
    const int* lpi = (const int*)lp;

    // per-n tables in registers
    float al0 = alpha[n],      al1 = alpha[32 + n];
    float al2 = alpha[64 + n], al3 = alpha[96 + n];
    float rv0 = rsp[n],        rv1 = rsp[32 + n];
    float rv2 = rsp[64 + n],   rv3 = rsp[96 + n];
    float sp0 = spp[n], sp1 = spp[32 + n], sp2 = spp[64 + n], sp3 = spp[96 + n];

    const float* opb = op + (size_t)PASS * 2 * NMAX_ * NO_;
    float W0[NO_], W1[NO_];
#pragma unroll
    for (int o = 0; o < NO_; ++o) {
        W0[o] = opb[(0 * NMAX_ + n) * NO_ + o];
        W1[o] = opb[(1 * NMAX_ + n) * NO_ + o];
    }

    // per-lane E pointer (element units): E[(b*NM + p0 + k)*32 + n]
    unsigned short* Ebl = nullptr;
    const unsigned short* Erd = nullptr;
    if constexpr (USE_E) {
        Ebl = E + ((size_t)b * NM_ + p0) * NMAX_ + n;
        Erd = Ebl;
    }

    // (PASS1) upfront csn2 gathers (both variants) and E loads (USE_E)
    float cj[32];
    unsigned short r[32];
    if constexpr (PASS == 1) {
#define LC(k) { int w_ = lpi[(k) * 4 + 3];                                   \
                int j_ = USE_E ? w_ : (w_ & 0x3fff);                         \
                cj[(k)] = csb[(size_t)j_ * NMAX_ + n]; }
#define LC8(k0) LC(k0) LC((k0)+1) LC((k0)+2) LC((k0)+3) \
                LC((k0)+4) LC((k0)+5) LC((k0)+6) LC((k0)+7)
        LC8(0)
        if (mseg > 8)  { LC8(8) }  else { cj[8]=cj[9]=cj[10]=cj[11]=cj[12]=cj[13]=cj[14]=cj[15]=0.f; }
        if (mseg > 16) { LC8(16) } else { cj[16]=cj[17]=cj[18]=cj[19]=cj[20]=cj[21]=cj[22]=cj[23]=0.f; }
        if (mseg > 24) { LC8(24) } else { cj[24]=cj[25]=cj[26]=cj[27]=cj[28]=cj[29]=cj[30]=cj[31]=0.f; }
#undef LC8
#undef LC
        if constexpr (USE_E) {
#define LDR(k) r[(k)] = Erd[(k) * NMAX_];
#define LDR8(k0) LDR(k0) LDR((k0)+1) LDR((k0)+2) LDR((k0)+3) \
                 LDR((k0)+4) LDR((k0)+5) LDR((k0)+6) LDR((k0)+7)
            LDR8(0)
            if (mseg > 8)  { LDR8(8) }  else { r[8]=r[9]=r[10]=r[11]=r[12]=r[13]=r[14]=r[15]=0; }
            if (mseg > 16) { LDR8(16) } else { r[16]=r[17]=r[18]=r[19]=r[20]=r[21]=r[22]=r[23]=0; }
            if (mseg > 24) { LDR8(24) } else { r[24]=r[25]=r[26]=r[27]=r[28]=r[29]=r[30]=r[31]=0; }
#undef LDR8
#undef LDR
        }
    }

    float acc0 = 0.f, acc1 = 0.f, acc2 = 0.f, acc3 = 0.f;

    if constexpr (PASS == 1 && USE_E) {
        // light KK: coef = E*cj
#define KK(k) {                                                              \
    float4 q_ = lp[(k)];                                                     \
    float coef_ = __half2float(__ushort_as_half(r[(k)])) * cj[(k)];          \
    coef_ = ((k) < seg) ? coef_ : 0.f;                                       \
    acc0 += coef_;                                                           \
    acc1 = fmaf(coef_, q_.x, acc1);                                          \
    acc2 = fmaf(coef_, q_.y, acc2);                                          \
    acc3 = fmaf(coef_, q_.z, acc3);                                          \
}
#define KK4(k0) if (mseg > (k0)) { KK(k0) KK((k0)+1) KK((k0)+2) KK((k0)+3) }
        KK4(0) KK4(4) KK4(8) KK4(12) KK4(16) KK4(20) KK4(24) KK4(28)
#undef KK4
#undef KK
    } else {
        // fused KK: selects + exp (+ E store on PASS0&&USE_E)
#define KK(k) {                                                              \
    float4 q_ = lp[(k)];                                                     \
    float2 df_ = ldf[(k)];                                                   \
    int w_ = __float_as_int(q_.w);                                           \
    bool s0_ = (w_ & (1 << 14)) != 0;                                        \
    bool s1_ = (w_ & (1 << 15)) != 0;                                        \
    float av_ = s1_ ? (s0_ ? al3 : al2) : (s0_ ? al1 : al0);                 \
    float rv_ = s1_ ? (s0_ ? rv3 : rv2) : (s0_ ? rv1 : rv0);                 \
    float dd_ = df_.x - rv_;                                                 \
    float e_ = __expf(av_ * dd_ * dd_);                                      \
    float Ef_ = e_ * df_.y;                                                  \
    if constexpr (PASS == 0 && USE_E) {                                      \
        if ((k) < seg)                                                       \
            Ebl[(k) * NMAX_] = __half_as_ushort(__float2half_rn(Ef_));       \
    }                                                                        \
    float cv_;                                                               \
    if constexpr (PASS == 0) {                                               \
        cv_ = s1_ ? (s0_ ? sp3 : sp2) : (s0_ ? sp1 : sp0);                   \
    } else {                                                                 \
        cv_ = cj[(k)];                                                       \
    }                                                                        \
    float coef_ = Ef_ * cv_;                                                 \
    coef_ = ((k) < seg) ? coef_ : 0.f;                                       \
    acc0 += coef_;                                                           \
    acc1 = fmaf(coef_, q_.x, acc1);                                          \
    acc2 = fmaf(coef_, q_.y, acc2);                                          \
    acc3 = fmaf(coef_, q_.z, acc3);                                          \
}
#define KK4(k0) if (mseg > (k0)) { KK(k0) KK((k0)+1) KK((k0)+2) KK((k0)+3) }
        KK4(0) KK4(4) KK4(8) KK4(12) KK4(16) KK4(20) KK4(24) KK4(28)
#undef KK4
#undef KK
    }

    // rare tail: segments longer than 32 pairs
    for (int p = p0 + 32; p < p1; ++p) {
        int j = jjb[p];
        float x = dpb[p * 3 + 0], y = dpb[p * 3 + 1], z = dpb[p * 3 + 2];
        float coef;
        if constexpr (PASS == 1 && USE_E) {
            float Ef = __half2float(__ushort_as_half(
                E[((size_t)b * NM_ + p) * NMAX_ + n]));
            coef = Ef * csb[(size_t)j * NMAX_ + n];
        } else {
            int jat = sorted_numbers[j];
            float dist = sqrtf(x * x + y * y + z * z);
            float c = __cosf(dist * (PI_F / 6.0f));
            float fc = 0.25f * (c + 1.f) * (c + 1.f);
            bool s0 = (jat & 1) != 0, s1 = (jat & 2) != 0;
            float av = s1 ? (s0 ? al3 : al2) : (s0 ? al1 : al0);
            float rv = s1 ? (s0 ? rv3 : rv2) : (s0 ? rv1 : rv0);
            float dd = dist - rv;
            float Ef = fc * __expf(av * dd * dd);
            if constexpr (PASS == 0 && USE_E)
                E[((size_t)b * NM_ + p) * NMAX_ + n] =
                    __half_as_ushort(__float2half_rn(Ef));
            float cv;
            if constexpr (PASS == 0)
                cv = s1 ? (s0 ? sp3 : sp2) : (s0 ? sp1 : sp0);
            else
                cv = csb[(size_t)j * NMAX_ + n];
            coef = Ef * cv;
        }
        acc0 += coef;
        acc1 = fmaf(coef, x, acc1);
        acc2 = fmaf(coef, y, acc2);
        acc3 = fmaf(coef, z, acc3);
    }

    // t[l][o] butterfly over the 32-lane half (each half = its own atom)
    float t[4][NO_];
#pragma unroll
    for (int o = 0; o < NO_; ++o) {
        t[0][o] = W0[o] * acc0;
        t[1][o] = W1[o] * acc1;
        t[2][o] = W1[o] * acc2;
        t[3][o] = W1[o] * acc3;
    }
#pragma unroll
    for (int off = 1; off < 32; off <<= 1) {
#pragma unroll
        for (int l = 0; l < 4; ++l)
#pragma unroll
            for (int o = 0; o < NO_; ++o)
                t[l][o] += __shfl_xor(t[l][o], off);
    }
    float rho[NO_];
#pragma unroll
    for (int o = 0; o < NO_; ++o)
        rho[o] = t[0][o] * t[0][o] + t[1][o] * t[1][o] +
                 t[2][o] * t[2][o] + t[3][o] * t[3][o];

    int hb = lane & 32;

    if constexpr (PASS == 1) {
        if (n == 0) {
            *reinterpret_cast<float4*>(out + (size_t)g * NO_) =
                make_float4(rho[0], rho[1], rho[2], rho[3]);
        }
    } else {
        // MLP: rho(4) -> h1(4,tanh) -> h2(38,tanh) -> 32, per atom-half
        float h1v[H1_];
#pragma unroll
        for (int k = 0; k < H1_; ++k) {
            float s = b1[k];
#pragma unroll
            for (int o = 0; o < NO_; ++o) s = fmaf(rho[o], w1[o * H1_ + k], s);
            h1v[k] = fast_tanh(s);
        }
        float sa = b2[n];
        int jbi = 32 + (n < 6 ? n : 5);
        float sb = b2[jbi];
#pragma unroll
        for (int k = 0; k < H1_; ++k) {
            sa = fmaf(h1v[k], w2[k * H2_ + n], sa);
            sb = fmaf(h1v[k], w2[k * H2_ + jbi], sb);
        }
        float hva = fast_tanh(sa);
        float hvb = fast_tanh(sb);
        float on = b3[n];
#pragma unroll
        for (int j2 = 0; j2 < 32; ++j2) {
            float hj = __shfl(hva, hb + j2);
            on = fmaf(hj, w3[j2 * NMAX_ + n], on);
        }
#pragma unroll
        for (int j2 = 0; j2 < 6; ++j2) {
            float hj = __shfl(hvb, hb + j2);
            on = fmaf(hj, w3[(32 + j2) * NMAX_ + n], on);
        }
        int aat = sorted_numbers[a];
        float basev = (aat & 2) ? ((aat & 1) ? sp3 : sp2)
                                : ((aat & 1) ? sp1 : sp0);
        csn2[(size_t)g * NMAX_ + n] = basev + on;
    }
}

extern "C" void kernel_launch(void* const* d_in, const int* in_sizes, int n_in,
                              void* d_out, int out_size, void* d_ws, size_t ws_size,
                              hipStream_t stream) {
    const float* disp = (const float*)d_in[0];
    const float* alpha = (const float*)d_in[1];
    const float* rsp = (const float*)d_in[2];
    const float* spp = (const float*)d_in[3];
    const float* op = (const float*)d_in[4];
    const float* w1 = (const float*)d_in[5];
    const float* b1 = (const float*)d_in[6];
    const float* w2 = (const float*)d_in[7];
    const float* b2 = (const float*)d_in[8];
    const float* w3 = (const float*)d_in[9];
    const float* b3 = (const float*)d_in[10];
    const int* iidx = (const int*)d_in[11];
    const int* jidx = (const int*)d_in[12];
    const int* sn = (const int*)d_in[13];
    float* out = (float*)d_out;

    float* csn2 = (float*)((char*)d_ws + CSN_OFF);
    int* starts = (int*)((char*)d_ws + ST_OFF);
    unsigned short* E = (unsigned short*)((char*)d_ws + E_OFF);

    int nthr = B_ * NM_;
    starts_kernel<<<(nthr + 255) / 256, 256, 0, stream>>>(iidx, starts);

    int ablocks = (B_ * NA_) / 8;          // 2 atoms/wave, 4 waves/block
    if (ws_size >= WS_NEED_E) {
        pass_kernel<0, 1><<<ablocks, 256, 0, stream>>>(disp, jidx, alpha, rsp,
                                                       spp, op, w1, b1, w2, b2,
                                                       w3, b3, sn, starts,
                                                       csn2, E, out);
        pass_kernel<1, 1><<<ablocks, 256, 0, stream>>>(disp, jidx, alpha, rsp,
                                                       spp, op, w1, b1, w2, b2,
                                                       w3, b3, sn, starts,
                                                       csn2, E, out);
    } else {
        pass_kernel<0, 0><<<ablocks, 256, 0, stream>>>(disp, jidx, alpha, rsp,
                                                       spp, op, w1, b1, w2, b2,
                                                       w3, b3, sn, starts,
                                                       csn2, E, out);
        pass_kernel<1, 0><<<ablocks, 256, 0, stream>>>(disp, jidx, alpha, rsp,
                                                       spp, op, w1, b1, w2, b2,
                                                       w3, b3, sn, starts,
                                                       csn2, E, out);
    }
}